// Round 3
// baseline (1235.202 us; speedup 1.0000x reference)
//
#include <hip/hip_runtime.h>
#include <math.h>

#define BB 16
#define NN 2000
#define CH 128
#define KNN 8

// ---------------------------------------------------------------------------
// helpers
// ---------------------------------------------------------------------------
__device__ inline float wred(float v) {
    for (int off = 32; off > 0; off >>= 1) v += __shfl_down(v, off, 64);
    return v;
}

// ---------------------------------------------------------------------------
// stage 0: t[b,c,n] = data[b,0,n,c]
// ---------------------------------------------------------------------------
__global__ void k_build_t(const float* __restrict__ data, float* __restrict__ t) {
    int i = blockIdx.x * 256 + threadIdx.x;
    if (i >= BB * 4 * NN) return;
    int n = i % NN;
    int c = (i / NN) & 3;
    int b = i / (4 * NN);
    t[i] = data[(b * NN + n) * 4 + c];
}

// conv1: c1[b,o,n] = sum_c w1a[o,c]*t[b,c,n] + b1a[o]
__global__ void k_conv1(const float* __restrict__ t, const float* __restrict__ w1a,
                        const float* __restrict__ b1a, float* __restrict__ c1) {
    int i = blockIdx.x * 256 + threadIdx.x;  // (b*128+o)*N+n
    if (i >= BB * CH * NN) return;
    int n = i % NN;
    int rest = i / NN;
    int o = rest & 127;
    int b = rest >> 7;
    float acc = b1a[o];
    for (int c = 0; c < 4; ++c) acc += w1a[o * 4 + c] * t[(b * 4 + c) * NN + n];
    c1[i] = acc;
}

// per-channel bn stats over (b,n): 128 blocks
__global__ void k_chanstats(const float* __restrict__ src, float* __restrict__ chAB) {
    int o = blockIdx.x;
    int tid = threadIdx.x;
    float s = 0.f, ss = 0.f;
    for (int b = 0; b < BB; ++b) {
        const float* p = src + (b * CH + o) * NN;
        for (int n = tid; n < NN; n += 256) { float v = p[n]; s += v; ss += v * v; }
    }
    s = wred(s); ss = wred(ss);
    __shared__ float sh[8];
    int wid = tid >> 6, lane = tid & 63;
    if (lane == 0) { sh[wid] = s; sh[4 + wid] = ss; }
    __syncthreads();
    if (tid == 0) {
        float S0 = sh[0] + sh[1] + sh[2] + sh[3];
        float SS = sh[4] + sh[5] + sh[6] + sh[7];
        float m = S0 / (float)(BB * NN);
        float var = SS / (float)(BB * NN) - m * m;
        float a = rsqrtf(var + 1e-5f);
        chAB[o] = a;
        chAB[CH + o] = -m * a;
    }
}

// ---------------------------------------------------------------------------
// generic 128x128 GEMM over columns (b,n), with input transform.
// mode 0: raw; mode 1: relu(chAB[j]*x + chAB[128+j]); mode 2: relu(ab[(b*128+j)*2]*x + ab[..+1])
// grid: (2, B*32), block 256.  tile: 64 o x 64 n.
// ---------------------------------------------------------------------------
__global__ __launch_bounds__(256) void k_gemm(const float* __restrict__ X, const float* __restrict__ W,
                                              const float* __restrict__ bias, float* __restrict__ Y,
                                              const float* __restrict__ ab, int mode) {
    int ot = blockIdx.x, by = blockIdx.y;
    int b = by >> 5, nt = by & 31;
    int n0 = nt * 64, o0 = ot * 64;
    int tid = threadIdx.x;
    int tx = tid & 15, ty = tid >> 4;
    __shared__ float Xs[32][64];
    __shared__ float Ws[32][65];
    float acc[4][4] = {};
    for (int jc = 0; jc < 4; ++jc) {
        for (int q = 0; q < 8; ++q) {
            int e = q * 256 + tid;
            int jj = e >> 6, nn = e & 63;
            int j = jc * 32 + jj, n = n0 + nn;
            float v = 0.f;
            if (n < NN) {
                v = X[(b * CH + j) * NN + n];
                if (mode == 1) v = fmaxf(ab[j] * v + ab[CH + j], 0.f);
                else if (mode == 2) { int bc = b * CH + j; v = fmaxf(ab[bc * 2] * v + ab[bc * 2 + 1], 0.f); }
            }
            Xs[jj][nn] = v;
        }
        for (int q = 0; q < 8; ++q) {
            int e = q * 256 + tid;
            int jj = e & 31, oo = e >> 5;
            Ws[jj][oo] = W[(o0 + oo) * CH + jc * 32 + jj];
        }
        __syncthreads();
        for (int jj = 0; jj < 32; ++jj) {
            float wv[4], xv[4];
#pragma unroll
            for (int q = 0; q < 4; ++q) wv[q] = Ws[jj][ty * 4 + q];
#pragma unroll
            for (int q = 0; q < 4; ++q) xv[q] = Xs[jj][tx * 4 + q];
#pragma unroll
            for (int a = 0; a < 4; ++a)
#pragma unroll
                for (int bq = 0; bq < 4; ++bq) acc[a][bq] += wv[a] * xv[bq];
        }
        __syncthreads();
    }
    for (int a = 0; a < 4; ++a) {
        int o = o0 + ty * 4 + a;
        float bi = bias[o];
        for (int q = 0; q < 4; ++q) {
            int n = n0 + tx * 4 + q;
            if (n < NN) Y[(b * CH + o) * NN + n] = acc[a][q] + bi;
        }
    }
}

// ---------------------------------------------------------------------------
// stage 1 tail: channel-norm, S, D, f5
// ---------------------------------------------------------------------------
__global__ void k_invn(const float* __restrict__ h2, float* __restrict__ invn) {
    int b = blockIdx.x >> 3, chunk = blockIdx.x & 7;
    int n = chunk * 256 + threadIdx.x;
    if (n >= NN) return;
    float acc = 0.f;
    for (int c = 0; c < CH; ++c) { float v = h2[(b * CH + c) * NN + n]; acc += v * v; }
    invn[b * NN + n] = 1.f / (sqrtf(acc) + 1e-5f);
}

__global__ void k_S(const float* __restrict__ h2, const float* __restrict__ invn, float* __restrict__ Sv) {
    int row = blockIdx.x;  // b*128+c
    int b = row >> 7;
    const float* p = h2 + row * NN;
    const float* iv = invn + b * NN;
    float s = 0.f;
    for (int n = threadIdx.x; n < NN; n += 256) s += p[n] * iv[n];
    s = wred(s);
    __shared__ float sh[4];
    int wid = threadIdx.x >> 6, lane = threadIdx.x & 63;
    if (lane == 0) sh[wid] = s;
    __syncthreads();
    if (threadIdx.x == 0) Sv[row] = sh[0] + sh[1] + sh[2] + sh[3];
}

__global__ void k_Df(const float* __restrict__ h2, const float* __restrict__ invn,
                     const float* __restrict__ Sv, const float* __restrict__ t,
                     float* __restrict__ outD, float* __restrict__ f5) {
    int b = blockIdx.x >> 3, chunk = blockIdx.x & 7;
    int n = chunk * 256 + threadIdx.x;
    if (n >= NN) return;
    float acc = 0.f;
    for (int c = 0; c < CH; ++c) acc += h2[(b * CH + c) * NN + n] * Sv[b * CH + c];
    float Ar = acc * invn[b * NN + n];
    float Dv = (Ar - 1.0f) / (float)NN;
    outD[b * NN + n] = Dv;
    for (int c = 0; c < 4; ++c) f5[(b * 5 + c) * NN + n] = t[(b * 4 + c) * NN + n];
    f5[(b * 5 + 4) * NN + n] = fmaxf(tanhf(Dv), 0.f);
}

// ---------------------------------------------------------------------------
// kNN: per (b,i) the 8 nearest (excluding self), stable ties (lower j first)
// ---------------------------------------------------------------------------
__global__ __launch_bounds__(256) void k_knn(const float* __restrict__ f5, int* __restrict__ idxb) {
    __shared__ float fs[5 * NN];
    int b = blockIdx.x >> 3, chunk = blockIdx.x & 7;
    for (int e = threadIdx.x; e < 5 * NN; e += 256) fs[e] = f5[b * 5 * NN + e];
    __syncthreads();
    int i = chunk * 256 + threadIdx.x;
    if (i >= NN) return;
    float fi0 = fs[i], fi1 = fs[NN + i], fi2 = fs[2 * NN + i], fi3 = fs[3 * NN + i], fi4 = fs[4 * NN + i];
    float bd[8]; int bj[8];
    for (int q = 0; q < 8; ++q) { bd[q] = 1e30f; bj[q] = -1; }
    float worst = 1e30f;
    for (int j = 0; j < NN; ++j) {
        float d0 = fi0 - fs[j], d1 = fi1 - fs[NN + j], d2 = fi2 - fs[2 * NN + j];
        float d3 = fi3 - fs[3 * NN + j], d4 = fi4 - fs[4 * NN + j];
        float d = d0 * d0 + d1 * d1 + d2 * d2 + d3 * d3 + d4 * d4;
        if (j == i) continue;
        if (d < worst) {
            int pos = 7;
            while (pos > 0 && d < bd[pos - 1]) { bd[pos] = bd[pos - 1]; bj[pos] = bj[pos - 1]; --pos; }
            bd[pos] = d; bj[pos] = j;
            worst = bd[7];
        }
    }
    for (int q = 0; q < 8; ++q) idxb[(b * NN + i) * 8 + q] = bj[q];
}

// ---------------------------------------------------------------------------
// graph-feature statistics: 10 means + 55 second moments (f64 accumulators)
// ---------------------------------------------------------------------------
__global__ __launch_bounds__(256) void k_gstats(const float* __restrict__ f5, const int* __restrict__ idxb,
                                                double* __restrict__ gacc) {
    int s = blockIdx.x * 256 + threadIdx.x;
    float acc[65];
#pragma unroll
    for (int q = 0; q < 65; ++q) acc[q] = 0.f;
    if (s < BB * NN) {
        int b = s / NN, n = s - b * NN;
        float fo[5];
#pragma unroll
        for (int c = 0; c < 5; ++c) fo[c] = f5[(b * 5 + c) * NN + n];
        float sd[5] = {0, 0, 0, 0, 0};
        float sdd[15];
#pragma unroll
        for (int q = 0; q < 15; ++q) sdd[q] = 0.f;
        for (int k = 0; k < 8; ++k) {
            int j = idxb[s * 8 + k];
            float df[5];
#pragma unroll
            for (int c = 0; c < 5; ++c) df[c] = fo[c] - f5[(b * 5 + c) * NN + j];
#pragma unroll
            for (int c = 0; c < 5; ++c) sd[c] += df[c];
            int t = 0;
#pragma unroll
            for (int c = 0; c < 5; ++c)
#pragma unroll
                for (int d2 = c; d2 < 5; ++d2) { sdd[t] += df[c] * df[d2]; ++t; }
        }
#pragma unroll
        for (int c = 0; c < 5; ++c) { acc[c] = 8.f * fo[c]; acc[5 + c] = sd[c]; }
        int t = 10, sc = 0;
        for (int p = 0; p < 10; ++p)
            for (int q = p; q < 10; ++q) {
                float v;
                if (q < 5) v = 8.f * fo[p] * fo[q];
                else if (p < 5) v = fo[p] * sd[q - 5];
                else { v = sdd[sc]; ++sc; }
                acc[t++] = v;
            }
    }
#pragma unroll 1
    for (int q = 0; q < 65; ++q) {
        float v = acc[q];
        for (int off = 32; off > 0; off >>= 1) v += __shfl_down(v, off, 64);
        acc[q] = v;
    }
    __shared__ float sh[4][65];
    int lane = threadIdx.x & 63, wid = threadIdx.x >> 6;
    if (lane == 0) {
        for (int q = 0; q < 65; ++q) sh[wid][q] = acc[q];
    }
    __syncthreads();
    if (threadIdx.x < 65) {
        float tot = sh[0][threadIdx.x] + sh[1][threadIdx.x] + sh[2][threadIdx.x] + sh[3][threadIdx.x];
        atomicAdd(&gacc[threadIdx.x], (double)tot);
    }
}

__global__ void k_gfinal(const double* __restrict__ gacc, const float* __restrict__ w2,
                         const float* __restrict__ b2, float* __restrict__ g2ab) {
    int o = threadIdx.x;
    if (o >= 128) return;
    double inv = 1.0 / (double)(BB * NN * 8);
    double Wr[10];
    for (int c = 0; c < 10; ++c) Wr[c] = (double)w2[o * 10 + c];
    double gm[10];
    for (int c = 0; c < 10; ++c) gm[c] = gacc[c] * inv;
    double b0 = (double)b2[o];
    double mean = b0;
    for (int c = 0; c < 10; ++c) mean += Wr[c] * gm[c];
    double e2 = b0 * b0 + 2.0 * b0 * (mean - b0);
    int t = 10;
    for (int p = 0; p < 10; ++p)
        for (int q = p; q < 10; ++q) {
            double G = gacc[t] * inv; ++t;
            double contrib = Wr[p] * Wr[q] * G;
            e2 += (p == q) ? contrib : 2.0 * contrib;
        }
    double var = e2 - mean * mean;
    double a = 1.0 / sqrt(var + 1e-5);
    g2ab[o] = (float)a;
    g2ab[128 + o] = (float)(-mean * a);
}

// graph conv + max over k + bn + relu (bn commutes with max since scale>0)
__global__ __launch_bounds__(256) void k_graphconv(const float* __restrict__ f5, const int* __restrict__ idxb,
                                                   const float* __restrict__ w2, const float* __restrict__ b2,
                                                   const float* __restrict__ g2ab, float* __restrict__ x0) {
    __shared__ float ws[1280], bs[128];
    __shared__ float fo_s[16][5], fnb_s[16][8][5];
    __shared__ int idxs[16][8];
    int b = blockIdx.x / 125, tile = blockIdx.x % 125;
    int nbase = tile * 16;
    int tid = threadIdx.x;
    for (int e = tid; e < 1280; e += 256) ws[e] = w2[e];
    if (tid < 128) bs[tid] = b2[tid];
    if (tid < 128) { int nn = tid >> 3, k = tid & 7; idxs[nn][k] = idxb[(b * NN + nbase + nn) * 8 + k]; }
    if (tid >= 128 && tid < 208) { int e = tid - 128; int nn = e / 5, c = e % 5; fo_s[nn][c] = f5[(b * 5 + c) * NN + nbase + nn]; }
    __syncthreads();
    for (int e = tid; e < 640; e += 256) {
        int nn = e / 40, r = e % 40, k = r / 5, c = r % 5;
        fnb_s[nn][k][c] = f5[(b * 5 + c) * NN + idxs[nn][k]];
    }
    __syncthreads();
    int nn = tid & 15, og = tid >> 4;
    float fo[5];
#pragma unroll
    for (int c = 0; c < 5; ++c) fo[c] = fo_s[nn][c];
    for (int oo = 0; oo < 8; ++oo) {
        int o = og * 8 + oo;
        float base = bs[o];
        float wn[5];
#pragma unroll
        for (int c = 0; c < 5; ++c) {
            float w1 = ws[o * 10 + c], w5 = ws[o * 10 + 5 + c];
            base += (w1 + w5) * fo[c];
            wn[c] = w5;
        }
        float mx = -1e30f;
        for (int k = 0; k < 8; ++k) {
            float v = base;
#pragma unroll
            for (int c = 0; c < 5; ++c) v -= wn[c] * fnb_s[nn][k][c];
            mx = fmaxf(mx, v);
        }
        float y = fmaxf(g2ab[o] * mx + g2ab[128 + o], 0.f);
        x0[(b * CH + o) * NN + nbase + nn] = y;
    }
}

// ---------------------------------------------------------------------------
// res-block support
// ---------------------------------------------------------------------------
__global__ void k_rowstats(const float* __restrict__ src, float* __restrict__ stats) {
    int row = blockIdx.x;  // b*128+c
    const float* p = src + row * NN;
    float s = 0.f, ss = 0.f;
    for (int n = threadIdx.x; n < NN; n += 256) { float v = p[n]; s += v; ss += v * v; }
    s = wred(s); ss = wred(ss);
    __shared__ float sh[8];
    int wid = threadIdx.x >> 6, lane = threadIdx.x & 63;
    if (lane == 0) { sh[wid] = s; sh[4 + wid] = ss; }
    __syncthreads();
    if (threadIdx.x == 0) {
        float S0 = sh[0] + sh[1] + sh[2] + sh[3];
        float SS = sh[4] + sh[5] + sh[6] + sh[7];
        float m = S0 / (float)NN;
        float var = SS / (float)NN - m * m;
        stats[row * 2] = m;
        stats[row * 2 + 1] = var;
    }
}

// instn + bn folded into per-(b,c) affine
__global__ void k_finalize(const float* __restrict__ stats, float* __restrict__ ab) {
    int c = threadIdx.x;
    if (c >= 128) return;
    float acc = 0.f;
    for (int b = 0; b < BB; ++b) { float var = stats[(b * CH + c) * 2 + 1]; acc += var / (var + 1e-5f); }
    float vc = acc / (float)BB;
    float sc = rsqrtf(vc + 1e-5f);
    for (int b = 0; b < BB; ++b) {
        float m = stats[(b * CH + c) * 2];
        float var = stats[(b * CH + c) * 2 + 1];
        float a = rsqrtf(var + 1e-5f) * sc;
        ab[(b * CH + c) * 2] = a;
        ab[(b * CH + c) * 2 + 1] = -m * a;
    }
}

__global__ void k_resadd(const float* __restrict__ Bm, const float* __restrict__ ab,
                         const float* __restrict__ x, float* __restrict__ y) {
    int i = blockIdx.x * 256 + threadIdx.x;
    if (i >= BB * CH * NN) return;
    int bc = i / NN;
    float v = ab[bc * 2] * Bm[i] + ab[bc * 2 + 1] + x[i];
    y[i] = fmaxf(v, 0.f);
}

// ---------------------------------------------------------------------------
// logit + weighted XwX
// ---------------------------------------------------------------------------
__global__ void k_logit(const float* __restrict__ x4, const float* __restrict__ wl,
                        const float* __restrict__ bl, float* __restrict__ outLogit) {
    int b = blockIdx.x >> 3, chunk = blockIdx.x & 7;
    int n = chunk * 256 + threadIdx.x;
    if (n >= NN) return;
    float acc = 0.f;
    for (int c = 0; c < CH; ++c) acc += wl[c] * x4[(b * CH + c) * NN + n];
    outLogit[b * NN + n] = acc + bl[0];
}

__global__ __launch_bounds__(256) void k_xwx(const float* __restrict__ logit, const float* __restrict__ x_in,
                                             float* __restrict__ XwX) {
    int b = blockIdx.x;
    int tid = threadIdx.x;
    float a[45];
#pragma unroll
    for (int q = 0; q < 45; ++q) a[q] = 0.f;
    for (int n = tid; n < NN; n += 256) {
        float lg = logit[b * NN + n];
        float w = fmaxf(tanhf(lg), 0.f);
        const float* xp = x_in + (b * NN + n) * 4;
        float px = xp[0], py = xp[1], z = xp[2], wq = xp[3];
        float X9[9] = {z * px, z * py, z, wq * px, wq * py, wq, px, py, 1.f};
        int t = 0;
#pragma unroll
        for (int p = 0; p < 9; ++p) {
            float wp = w * X9[p];
#pragma unroll
            for (int q = p; q < 9; ++q) { a[t] += wp * X9[q]; ++t; }
        }
    }
#pragma unroll 1
    for (int q = 0; q < 45; ++q) {
        float v = a[q];
        for (int off = 32; off > 0; off >>= 1) v += __shfl_down(v, off, 64);
        a[q] = v;
    }
    __shared__ float sh[4][45];
    int lane = tid & 63, wid = tid >> 6;
    if (lane == 0) {
        for (int q = 0; q < 45; ++q) sh[wid][q] = a[q];
    }
    __syncthreads();
    if (tid < 45) XwX[b * 45 + tid] = sh[0][tid] + sh[1][tid] + sh[2][tid] + sh[3][tid];
}

// ---------------------------------------------------------------------------
// 9x9 symmetric eigensolver — faithful LAPACK **ssyevd** (single precision!)
// small-N path emulation: ssytd2 (lower) + ssteqr + sormtr back-transform,
// all in f32 with f32 LAPACK constants, and the LAPACK >=3.10 slartg
// convention (c >= 0 always).  Rationale: the np reference runs
// np.linalg.eigh on a float32 XwX -> ssyevd; eigenvector SIGN depends on the
// rotation history, which depends on f32-trajectory discrete decisions
// (block splits, QL-vs-QR choice) made with eps=2^-24.  An f64 emulation
// diverges on those decisions (round-1: one flipped batch).  The c>=0
// slartg makes near-converged rotations ~ +identity, so signs are robust to
// ulp-level differences — matching is feasible exactly in this regime.
// ---------------------------------------------------------------------------
__device__ inline float slapy2_f(float x, float y) {
    float xa = fabsf(x), ya = fabsf(y);
    float w = fmaxf(xa, ya), z = fminf(xa, ya);
    if (z == 0.f) return w;
    float q = z / w;
    return w * sqrtf(1.f + q * q);
}

// LAPACK >= 3.10 slartg: c = |f|/r >= 0, r = sign(f)*hypot, s = g/r
__device__ inline void slartg_f(float f, float g, float& c, float& s, float& r) {
    if (g == 0.f) { c = 1.f; s = 0.f; r = f; }
    else if (f == 0.f) { c = 0.f; s = (g > 0.f ? 1.f : -1.f); r = fabsf(g); }
    else {
        float d = sqrtf(f * f + g * g);
        c = fabsf(f) / d;
        r = (f >= 0.f) ? d : -d;
        s = g / r;
    }
}

__device__ void slaev2_f(float a, float b, float c, float& rt1, float& rt2, float& cs1, float& sn1) {
    float sm = a + c, df = a - c;
    float adf = fabsf(df), tb = b + b, ab = fabsf(tb);
    float acmx, acmn;
    if (fabsf(a) > fabsf(c)) { acmx = a; acmn = c; } else { acmx = c; acmn = a; }
    float rt;
    if (adf > ab) { float q = ab / adf; rt = adf * sqrtf(1.f + q * q); }
    else if (adf < ab) { float q = adf / ab; rt = ab * sqrtf(1.f + q * q); }
    else rt = ab * sqrtf(2.f);
    int sgn1;
    if (sm < 0.f) { rt1 = 0.5f * (sm - rt); sgn1 = -1; rt2 = (acmx / rt1) * acmn - (b / rt1) * b; }
    else if (sm > 0.f) { rt1 = 0.5f * (sm + rt); sgn1 = 1; rt2 = (acmx / rt1) * acmn - (b / rt1) * b; }
    else { rt1 = 0.5f * rt; rt2 = -0.5f * rt; sgn1 = 1; }
    float cs; int sgn2;
    if (df >= 0.f) { cs = df + rt; sgn2 = 1; } else { cs = df - rt; sgn2 = -1; }
    float acs = fabsf(cs);
    if (acs > ab) {
        float ct = -tb / cs;
        sn1 = 1.f / sqrtf(1.f + ct * ct);
        cs1 = ct * sn1;
    } else {
        if (ab == 0.f) { cs1 = 1.f; sn1 = 0.f; }
        else { float tn = -cs / tb; cs1 = 1.f / sqrtf(1.f + tn * tn); sn1 = tn * cs1; }
    }
    if (sgn1 == sgn2) { float tn = cs1; cs1 = -sn1; sn1 = tn; }
}

__global__ __launch_bounds__(64) void k_eigh(const float* __restrict__ XwX, float* __restrict__ out_e) {
    __shared__ float shA[16 * 81];
    __shared__ float shZ[16 * 81];
    int bb = threadIdx.x;
    if (bb >= 16) return;
    float* Am = shA + bb * 81;
    float* Zm = shZ + bb * 81;
#define AA(i, j) Am[(i) * 9 + (j)]
#define ZZ(i, j) Zm[(i) * 9 + (j)]
    {
        const float* src = XwX + bb * 45;
        int t = 0;
        for (int p = 0; p < 9; ++p)
            for (int q = p; q < 9; ++q) { float v = src[t++]; AA(p, q) = v; AA(q, p) = v; }
    }
    float d[9], e[9], tau[9];
    // --- ssytd2 (lower) ---
    for (int i = 0; i < 8; ++i) {
        float alpha = AA(i + 1, i);
        float xn2 = 0.f;
        for (int j = i + 2; j < 9; ++j) xn2 += AA(j, i) * AA(j, i);
        float taui;
        if (xn2 == 0.f) { taui = 0.f; e[i] = alpha; }
        else {
            float xnorm = sqrtf(xn2);
            float beta = slapy2_f(alpha, xnorm);
            beta = (alpha >= 0.f) ? -beta : beta;
            taui = (beta - alpha) / beta;
            float scl = 1.f / (alpha - beta);
            for (int j = i + 2; j < 9; ++j) AA(j, i) *= scl;
            e[i] = beta;
            float p[9], w[9];
            for (int j = i + 1; j < 9; ++j) {
                float acc = AA(j, i + 1);
                for (int k2 = i + 2; k2 < 9; ++k2) acc += AA(j, k2) * AA(k2, i);
                p[j] = taui * acc;
            }
            float dot = p[i + 1];
            for (int j = i + 2; j < 9; ++j) dot += p[j] * AA(j, i);
            float alpha2 = -0.5f * taui * dot;
            w[i + 1] = p[i + 1] + alpha2;
            for (int j = i + 2; j < 9; ++j) w[j] = p[j] + alpha2 * AA(j, i);
            for (int j = i + 1; j < 9; ++j) {
                float vj = (j == i + 1) ? 1.f : AA(j, i);
                for (int k2 = i + 1; k2 < 9; ++k2) {
                    float vk = (k2 == i + 1) ? 1.f : AA(k2, i);
                    AA(j, k2) -= vj * w[k2] + w[j] * vk;
                }
            }
        }
        tau[i] = taui;
    }
    for (int i = 0; i < 9; ++i) d[i] = AA(i, i);
    for (int i = 0; i < 81; ++i) Zm[i] = 0.f;
    for (int i = 0; i < 9; ++i) ZZ(i, i) = 1.f;
    // --- ssteqr (f32 constants: eps = slamch('E') = 2^-24) ---
    const float eps = 5.9604645e-08f;
    const float eps2 = 3.5527137e-15f;
    const float safmin = 1.17549435e-38f;
    const int n = 9;
    int nmaxit = n * 30, jtot = 0;
    int l1 = 0;
    while (l1 <= n - 1) {
        if (l1 > 0) e[l1 - 1] = 0.f;
        int m = n - 1;
        for (int mm = l1; mm <= n - 2; ++mm) {
            float tst = fabsf(e[mm]);
            if (tst == 0.f) { m = mm; break; }
            if (tst <= (sqrtf(fabsf(d[mm])) * sqrtf(fabsf(d[mm + 1]))) * eps) { e[mm] = 0.f; m = mm; break; }
        }
        int l = l1, lsv = l, lend = m, lendsv = lend;
        l1 = m + 1;
        if (lend == l) continue;
        if (fabsf(d[lend]) < fabsf(d[l])) { lend = lsv; l = lendsv; }
        if (lend > l) {
            // QL
            for (;;) {
                int m2 = lend;
                if (l != lend) {
                    for (int mm = l; mm <= lend - 1; ++mm) {
                        float tst = e[mm] * e[mm];
                        if (tst <= (eps2 * fabsf(d[mm])) * fabsf(d[mm + 1]) + safmin) { m2 = mm; break; }
                    }
                }
                if (m2 < lend) e[m2] = 0.f;
                float p = d[l];
                if (m2 == l) { d[l] = p; ++l; if (l <= lend) continue; else break; }
                if (m2 == l + 1) {
                    float rt1, rt2, c, s;
                    slaev2_f(d[l], e[l], d[l + 1], rt1, rt2, c, s);
                    for (int r2 = 0; r2 < 9; ++r2) {
                        float tmp = ZZ(r2, l + 1);
                        ZZ(r2, l + 1) = c * tmp - s * ZZ(r2, l);
                        ZZ(r2, l) = s * tmp + c * ZZ(r2, l);
                    }
                    d[l] = rt1; d[l + 1] = rt2; e[l] = 0.f; l += 2;
                    if (l <= lend) continue; else break;
                }
                if (jtot == nmaxit) break;
                ++jtot;
                float g = (d[l + 1] - p) / (2.f * e[l]);
                float r = slapy2_f(g, 1.f);
                g = d[m2] - p + e[l] / (g + (g >= 0.f ? fabsf(r) : -fabsf(r)));
                float s = 1.f, c = 1.f;
                p = 0.f;
                float csv[9], snv[9];
                for (int i = m2 - 1; i >= l; --i) {
                    float f = s * e[i], bq = c * e[i];
                    slartg_f(g, f, c, s, r);
                    if (i != m2 - 1) e[i + 1] = r;
                    g = d[i + 1] - p;
                    r = (d[i] - g) * s + 2.f * c * bq;
                    p = s * r;
                    d[i + 1] = g + p;
                    g = c * r - bq;
                    csv[i] = c; snv[i] = -s;
                }
                for (int jj = m2 - 1; jj >= l; --jj) {
                    float cj = csv[jj], sj = snv[jj];
                    for (int r2 = 0; r2 < 9; ++r2) {
                        float tmp = ZZ(r2, jj + 1);
                        ZZ(r2, jj + 1) = cj * tmp - sj * ZZ(r2, jj);
                        ZZ(r2, jj) = sj * tmp + cj * ZZ(r2, jj);
                    }
                }
                d[l] -= p; e[l] = g;
            }
        } else {
            // QR
            for (;;) {
                int m2 = lend;
                if (l != lend) {
                    for (int mm = l; mm >= lend + 1; --mm) {
                        float tst = e[mm - 1] * e[mm - 1];
                        if (tst <= (eps2 * fabsf(d[mm])) * fabsf(d[mm - 1]) + safmin) { m2 = mm; break; }
                    }
                }
                if (m2 > lend) e[m2 - 1] = 0.f;
                float p = d[l];
                if (m2 == l) { d[l] = p; --l; if (l >= lend) continue; else break; }
                if (m2 == l - 1) {
                    float rt1, rt2, c, s;
                    slaev2_f(d[l - 1], e[l - 1], d[l], rt1, rt2, c, s);
                    for (int r2 = 0; r2 < 9; ++r2) {
                        float tmp = ZZ(r2, l);
                        ZZ(r2, l) = c * tmp - s * ZZ(r2, l - 1);
                        ZZ(r2, l - 1) = s * tmp + c * ZZ(r2, l - 1);
                    }
                    d[l - 1] = rt1; d[l] = rt2; e[l - 1] = 0.f; l -= 2;
                    if (l >= lend) continue; else break;
                }
                if (jtot == nmaxit) break;
                ++jtot;
                float g = (d[l - 1] - p) / (2.f * e[l - 1]);
                float r = slapy2_f(g, 1.f);
                g = d[m2] - p + e[l - 1] / (g + (g >= 0.f ? fabsf(r) : -fabsf(r)));
                float s = 1.f, c = 1.f;
                p = 0.f;
                float csv[9], snv[9];
                for (int i = m2; i <= l - 1; ++i) {
                    float f = s * e[i], bq = c * e[i];
                    slartg_f(g, f, c, s, r);
                    if (i != m2) e[i - 1] = r;
                    g = d[i] - p;
                    r = (d[i + 1] - g) * s + 2.f * c * bq;
                    p = s * r;
                    d[i] = g + p;
                    g = c * r - bq;
                    csv[i] = c; snv[i] = s;
                }
                for (int jj = m2; jj <= l - 1; ++jj) {
                    float cj = csv[jj], sj = snv[jj];
                    for (int r2 = 0; r2 < 9; ++r2) {
                        float tmp = ZZ(r2, jj + 1);
                        ZZ(r2, jj + 1) = cj * tmp - sj * ZZ(r2, jj);
                        ZZ(r2, jj) = sj * tmp + cj * ZZ(r2, jj);
                    }
                }
                d[l] -= p; e[l - 1] = g;
            }
        }
    }
    // selection sort ascending (swap columns)
    for (int ii = 1; ii < 9; ++ii) {
        int i = ii - 1, kk = i;
        float p = d[i];
        for (int j = ii; j < 9; ++j)
            if (d[j] < p) { kk = j; p = d[j]; }
        if (kk != i) {
            d[kk] = d[i]; d[i] = p;
            for (int r2 = 0; r2 < 9; ++r2) { float tmp = ZZ(r2, i); ZZ(r2, i) = ZZ(r2, kk); ZZ(r2, kk) = tmp; }
        }
    }
    // back-transform column 0 by Q (sormtr 'L','L','N': apply H(8)..H(1))
    float v0[9];
    for (int r2 = 0; r2 < 9; ++r2) v0[r2] = ZZ(r2, 0);
    for (int i = 7; i >= 0; --i) {
        float ti = tau[i];
        if (ti == 0.f) continue;
        float dot = v0[i + 1];
        for (int j = i + 2; j < 9; ++j) dot += AA(j, i) * v0[j];
        dot *= ti;
        v0[i + 1] -= dot;
        for (int j = i + 2; j < 9; ++j) v0[j] -= AA(j, i) * dot;
    }
    float nrm = 0.f;
    for (int r2 = 0; r2 < 9; ++r2) nrm += v0[r2] * v0[r2];
    nrm = sqrtf(nrm);
    for (int r2 = 0; r2 < 9; ++r2) out_e[bb * 9 + r2] = v0[r2] / nrm;
#undef AA
#undef ZZ
}

// ---------------------------------------------------------------------------
// launch
// ---------------------------------------------------------------------------
extern "C" void kernel_launch(void* const* d_in, const int* in_sizes, int n_in,
                              void* d_out, int out_size, void* d_ws, size_t ws_size,
                              hipStream_t stream) {
    const float* data = (const float*)d_in[0];
    const float* x_in = (const float*)d_in[1];
    const float* w1a = (const float*)d_in[2];
    const float* b1a = (const float*)d_in[3];
    const float* w1b = (const float*)d_in[4];
    const float* b1b = (const float*)d_in[5];
    const float* w2 = (const float*)d_in[6];
    const float* b2 = (const float*)d_in[7];
    const float* res_wa = (const float*)d_in[8];
    const float* res_ba = (const float*)d_in[9];
    const float* res_wb = (const float*)d_in[10];
    const float* res_bb = (const float*)d_in[11];
    const float* wl = (const float*)d_in[12];
    const float* bl = (const float*)d_in[13];
    float* out = (float*)d_out;

    // workspace layout
    double* gacc = (double*)d_ws;                       // 65 doubles (needs memset)
    float* xwx = (float*)((char*)d_ws + 1024);          // 16*45 floats
    float* fbase = (float*)((char*)d_ws + 8192);
    float* big0 = fbase;
    float* big1 = big0 + BB * CH * NN;
    float* big2 = big1 + BB * CH * NN;
    float* tbuf = big2 + BB * CH * NN;
    float* f5 = tbuf + BB * 4 * NN;
    float* invn = f5 + BB * 5 * NN;
    float* Sv = invn + BB * NN;
    int* idxb = (int*)(Sv + BB * CH);
    float* chAB = (float*)(idxb + BB * NN * 8);
    float* stA = chAB + 256;
    float* abA = stA + BB * CH * 2;
    float* stB = abA + BB * CH * 2;
    float* abB = stB + BB * CH * 2;
    float* g2ab = abB + BB * CH * 2;

    hipMemsetAsync(d_ws, 0, 1024, stream);

    k_build_t<<<500, 256, 0, stream>>>(data, tbuf);
    k_conv1<<<16000, 256, 0, stream>>>(tbuf, w1a, b1a, big0);
    k_chanstats<<<128, 256, 0, stream>>>(big0, chAB);
    k_gemm<<<dim3(2, 512), 256, 0, stream>>>(big0, w1b, b1b, big1, chAB, 1);  // h2 in big1
    k_invn<<<128, 256, 0, stream>>>(big1, invn);
    k_S<<<2048, 256, 0, stream>>>(big1, invn, Sv);
    k_Df<<<128, 256, 0, stream>>>(big1, invn, Sv, tbuf, out, f5);
    k_knn<<<128, 256, 0, stream>>>(f5, idxb);
    k_gstats<<<125, 256, 0, stream>>>(f5, idxb, gacc);
    k_gfinal<<<1, 128, 0, stream>>>(gacc, w2, b2, g2ab);
    k_graphconv<<<2000, 256, 0, stream>>>(f5, idxb, w2, b2, g2ab, big0);  // x0 in big0

    float* xb = big0;
    float* hb = big1;
    for (int i = 0; i < 4; ++i) {
        k_gemm<<<dim3(2, 512), 256, 0, stream>>>(xb, res_wa + i * CH * CH, res_ba + i * CH, hb, nullptr, 0);
        k_rowstats<<<2048, 256, 0, stream>>>(hb, stA);
        k_finalize<<<1, 128, 0, stream>>>(stA, abA);
        k_gemm<<<dim3(2, 512), 256, 0, stream>>>(hb, res_wb + i * CH * CH, res_bb + i * CH, big2, abA, 2);
        k_rowstats<<<2048, 256, 0, stream>>>(big2, stB);
        k_finalize<<<1, 128, 0, stream>>>(stB, abB);
        k_resadd<<<16000, 256, 0, stream>>>(big2, abB, xb, hb);
        float* tmp = xb; xb = hb; hb = tmp;
    }

    k_logit<<<128, 256, 0, stream>>>(xb, wl, bl, out + BB * NN);
    k_xwx<<<16, 256, 0, stream>>>(out + BB * NN, x_in, xwx);
    k_eigh<<<1, 64, 0, stream>>>(xwx, out + 2 * BB * NN);
}

// Round 4
// 1060.479 us; speedup vs baseline: 1.1648x; 1.1648x over previous
//
#include <hip/hip_runtime.h>
#include <math.h>

#define BB 16
#define NN 2000
#define CH 128
#define KNN 8
#define JCH 8
#define JSZ 250  // NN / JCH

// ---------------------------------------------------------------------------
// helpers
// ---------------------------------------------------------------------------
__device__ inline float wred(float v) {
    for (int off = 32; off > 0; off >>= 1) v += __shfl_down(v, off, 64);
    return v;
}

// ---------------------------------------------------------------------------
// stage 0: t[b,c,n] = data[b,0,n,c]
// ---------------------------------------------------------------------------
__global__ void k_build_t(const float* __restrict__ data, float* __restrict__ t) {
    int i = blockIdx.x * 256 + threadIdx.x;
    if (i >= BB * 4 * NN) return;
    int n = i % NN;
    int c = (i / NN) & 3;
    int b = i / (4 * NN);
    t[i] = data[(b * NN + n) * 4 + c];
}

// conv1: c1[b,o,n] = sum_c w1a[o,c]*t[b,c,n] + b1a[o]
__global__ void k_conv1(const float* __restrict__ t, const float* __restrict__ w1a,
                        const float* __restrict__ b1a, float* __restrict__ c1) {
    int i = blockIdx.x * 256 + threadIdx.x;  // (b*128+o)*N+n
    if (i >= BB * CH * NN) return;
    int n = i % NN;
    int rest = i / NN;
    int o = rest & 127;
    int b = rest >> 7;
    float acc = b1a[o];
    for (int c = 0; c < 4; ++c) acc += w1a[o * 4 + c] * t[(b * 4 + c) * NN + n];
    c1[i] = acc;
}

// per-channel bn stats over (b,n): 128 blocks
__global__ void k_chanstats(const float* __restrict__ src, float* __restrict__ chAB) {
    int o = blockIdx.x;
    int tid = threadIdx.x;
    float s = 0.f, ss = 0.f;
    for (int b = 0; b < BB; ++b) {
        const float* p = src + (b * CH + o) * NN;
        for (int n = tid; n < NN; n += 256) { float v = p[n]; s += v; ss += v * v; }
    }
    s = wred(s); ss = wred(ss);
    __shared__ float sh[8];
    int wid = tid >> 6, lane = tid & 63;
    if (lane == 0) { sh[wid] = s; sh[4 + wid] = ss; }
    __syncthreads();
    if (tid == 0) {
        float S0 = sh[0] + sh[1] + sh[2] + sh[3];
        float SS = sh[4] + sh[5] + sh[6] + sh[7];
        float m = S0 / (float)(BB * NN);
        float var = SS / (float)(BB * NN) - m * m;
        float a = rsqrtf(var + 1e-5f);
        chAB[o] = a;
        chAB[CH + o] = -m * a;
    }
}

// ---------------------------------------------------------------------------
// generic 128x128 GEMM over columns (b,n), with input transform.
// mode 0: raw; mode 1: relu(chAB[j]*x + chAB[128+j]); mode 2: relu(ab[(b*128+j)*2]*x + ab[..+1])
// grid: (2, B*32), block 256.  tile: 64 o x 64 n.
// Ws padded to 68 floats/row (272 B, 16 B aligned) so fragment reads are
// ds_read_b128.  FMA accumulation order is IDENTICAL to the r3 baseline —
// do not reorder (absmax margin 0.34/0.4225 depends on it).
// ---------------------------------------------------------------------------
__global__ __launch_bounds__(256) void k_gemm(const float* __restrict__ X, const float* __restrict__ W,
                                              const float* __restrict__ bias, float* __restrict__ Y,
                                              const float* __restrict__ ab, int mode) {
    int ot = blockIdx.x, by = blockIdx.y;
    int b = by >> 5, nt = by & 31;
    int n0 = nt * 64, o0 = ot * 64;
    int tid = threadIdx.x;
    int tx = tid & 15, ty = tid >> 4;
    __shared__ float Xs[32][64];
    __shared__ float Ws[32][68];
    float acc[4][4] = {};
    for (int jc = 0; jc < 4; ++jc) {
        for (int q = 0; q < 8; ++q) {
            int e = q * 256 + tid;
            int jj = e >> 6, nn = e & 63;
            int j = jc * 32 + jj, n = n0 + nn;
            float v = 0.f;
            if (n < NN) {
                v = X[(b * CH + j) * NN + n];
                if (mode == 1) v = fmaxf(ab[j] * v + ab[CH + j], 0.f);
                else if (mode == 2) { int bc = b * CH + j; v = fmaxf(ab[bc * 2] * v + ab[bc * 2 + 1], 0.f); }
            }
            Xs[jj][nn] = v;
        }
        for (int q = 0; q < 8; ++q) {
            int e = q * 256 + tid;
            int jj = e & 31, oo = e >> 5;
            Ws[jj][oo] = W[(o0 + oo) * CH + jc * 32 + jj];
        }
        __syncthreads();
        for (int jj = 0; jj < 32; ++jj) {
            float4 wv = *(const float4*)&Ws[jj][ty * 4];
            float4 xv = *(const float4*)&Xs[jj][tx * 4];
            float wva[4] = {wv.x, wv.y, wv.z, wv.w};
            float xva[4] = {xv.x, xv.y, xv.z, xv.w};
#pragma unroll
            for (int a = 0; a < 4; ++a)
#pragma unroll
                for (int bq = 0; bq < 4; ++bq) acc[a][bq] += wva[a] * xva[bq];
        }
        __syncthreads();
    }
    for (int a = 0; a < 4; ++a) {
        int o = o0 + ty * 4 + a;
        float bi = bias[o];
        for (int q = 0; q < 4; ++q) {
            int n = n0 + tx * 4 + q;
            if (n < NN) Y[(b * CH + o) * NN + n] = acc[a][q] + bi;
        }
    }
}

// ---------------------------------------------------------------------------
// stage 1 tail: channel-norm, S, D, f5
// ---------------------------------------------------------------------------
__global__ void k_invn(const float* __restrict__ h2, float* __restrict__ invn) {
    int b = blockIdx.x >> 3, chunk = blockIdx.x & 7;
    int n = chunk * 256 + threadIdx.x;
    if (n >= NN) return;
    float acc = 0.f;
    for (int c = 0; c < CH; ++c) { float v = h2[(b * CH + c) * NN + n]; acc += v * v; }
    invn[b * NN + n] = 1.f / (sqrtf(acc) + 1e-5f);
}

__global__ void k_S(const float* __restrict__ h2, const float* __restrict__ invn, float* __restrict__ Sv) {
    int row = blockIdx.x;  // b*128+c
    int b = row >> 7;
    const float* p = h2 + row * NN;
    const float* iv = invn + b * NN;
    float s = 0.f;
    for (int n = threadIdx.x; n < NN; n += 256) s += p[n] * iv[n];
    s = wred(s);
    __shared__ float sh[4];
    int wid = threadIdx.x >> 6, lane = threadIdx.x & 63;
    if (lane == 0) sh[wid] = s;
    __syncthreads();
    if (threadIdx.x == 0) Sv[row] = sh[0] + sh[1] + sh[2] + sh[3];
}

__global__ void k_Df(const float* __restrict__ h2, const float* __restrict__ invn,
                     const float* __restrict__ Sv, const float* __restrict__ t,
                     float* __restrict__ outD, float* __restrict__ f5) {
    int b = blockIdx.x >> 3, chunk = blockIdx.x & 7;
    int n = chunk * 256 + threadIdx.x;
    if (n >= NN) return;
    float acc = 0.f;
    for (int c = 0; c < CH; ++c) acc += h2[(b * CH + c) * NN + n] * Sv[b * CH + c];
    float Ar = acc * invn[b * NN + n];
    float Dv = (Ar - 1.0f) / (float)NN;
    outD[b * NN + n] = Dv;
    for (int c = 0; c < 4; ++c) f5[(b * 5 + c) * NN + n] = t[(b * 4 + c) * NN + n];
    f5[(b * 5 + 4) * NN + n] = fmaxf(tanhf(Dv), 0.f);
}

// ---------------------------------------------------------------------------
// kNN stage A: per (b, i, j-chunk) partial top-8 over 250 candidates.
// grid (JCH, 8, BB) = 1024 blocks (r3's single-kernel version had 128 blocks
// -> 5.7% occupancy, 388 us, latency-bound).  Distance arithmetic is
// bit-identical to r3; chunk-local stable insertion (strict <) preserves
// lower-j-first on ties within a chunk.
// ---------------------------------------------------------------------------
__global__ __launch_bounds__(256) void k_knn_part(const float* __restrict__ f5,
                                                  float* __restrict__ pd, int* __restrict__ pj) {
    __shared__ float fs[5][JSZ];
    int jc = blockIdx.x, ic = blockIdx.y, b = blockIdx.z;
    int j0 = jc * JSZ;
    int tid = threadIdx.x;
    for (int e = tid; e < 5 * JSZ; e += 256) {
        int c = e / JSZ, jj = e - c * JSZ;
        fs[c][jj] = f5[(b * 5 + c) * NN + j0 + jj];
    }
    __syncthreads();
    int i = ic * 256 + tid;
    if (i >= NN) return;
    float fi0 = f5[(b * 5 + 0) * NN + i], fi1 = f5[(b * 5 + 1) * NN + i],
          fi2 = f5[(b * 5 + 2) * NN + i], fi3 = f5[(b * 5 + 3) * NN + i],
          fi4 = f5[(b * 5 + 4) * NN + i];
    float bd[8]; int bj[8];
    for (int q = 0; q < 8; ++q) { bd[q] = 1e30f; bj[q] = 0x7fffffff; }
    float worst = 1e30f;
    for (int jj = 0; jj < JSZ; ++jj) {
        int j = j0 + jj;
        float d0 = fi0 - fs[0][jj], d1 = fi1 - fs[1][jj], d2 = fi2 - fs[2][jj];
        float d3 = fi3 - fs[3][jj], d4 = fi4 - fs[4][jj];
        float d = d0 * d0 + d1 * d1 + d2 * d2 + d3 * d3 + d4 * d4;
        if (j == i) continue;
        if (d < worst) {
            int pos = 7;
            while (pos > 0 && d < bd[pos - 1]) { bd[pos] = bd[pos - 1]; bj[pos] = bj[pos - 1]; --pos; }
            bd[pos] = d; bj[pos] = j;
            worst = bd[7];
        }
    }
    long base = ((long)(b * NN + i) * JCH + jc) * 8;
    for (int q = 0; q < 8; ++q) { pd[base + q] = bd[q]; pj[base + q] = bj[q]; }
}

// kNN stage B: 8-way merge of sorted partial lists.  Tie-break (d equal ->
// lower j) reproduces the global ascending-j stable scan exactly (chunk
// order == j order).
__global__ __launch_bounds__(256) void k_knn_merge(const float* __restrict__ pd, const int* __restrict__ pj,
                                                   int* __restrict__ idxb) {
    int s = blockIdx.x * 256 + threadIdx.x;  // b*NN + i
    if (s >= BB * NN) return;
    const float* dl = pd + (long)s * JCH * 8;
    const int* jl = pj + (long)s * JCH * 8;
    int ptr[JCH];
#pragma unroll
    for (int c = 0; c < JCH; ++c) ptr[c] = 0;
    for (int q = 0; q < 8; ++q) {
        float best = 1e38f; int bestj = 0x7fffffff; int bc = 0;
#pragma unroll
        for (int c = 0; c < JCH; ++c) {
            if (ptr[c] < 8) {
                float d = dl[c * 8 + ptr[c]];
                int j = jl[c * 8 + ptr[c]];
                if (d < best || (d == best && j < bestj)) { best = d; bestj = j; bc = c; }
            }
        }
        idxb[s * 8 + q] = bestj;
        ++ptr[bc];
    }
}

// ---------------------------------------------------------------------------
// graph-feature statistics: 10 means + 55 second moments (f64 accumulators)
// ---------------------------------------------------------------------------
__global__ __launch_bounds__(256) void k_gstats(const float* __restrict__ f5, const int* __restrict__ idxb,
                                                double* __restrict__ gacc) {
    int s = blockIdx.x * 256 + threadIdx.x;
    float acc[65];
#pragma unroll
    for (int q = 0; q < 65; ++q) acc[q] = 0.f;
    if (s < BB * NN) {
        int b = s / NN, n = s - b * NN;
        float fo[5];
#pragma unroll
        for (int c = 0; c < 5; ++c) fo[c] = f5[(b * 5 + c) * NN + n];
        float sd[5] = {0, 0, 0, 0, 0};
        float sdd[15];
#pragma unroll
        for (int q = 0; q < 15; ++q) sdd[q] = 0.f;
        for (int k = 0; k < 8; ++k) {
            int j = idxb[s * 8 + k];
            float df[5];
#pragma unroll
            for (int c = 0; c < 5; ++c) df[c] = fo[c] - f5[(b * 5 + c) * NN + j];
#pragma unroll
            for (int c = 0; c < 5; ++c) sd[c] += df[c];
            int t = 0;
#pragma unroll
            for (int c = 0; c < 5; ++c)
#pragma unroll
                for (int d2 = c; d2 < 5; ++d2) { sdd[t] += df[c] * df[d2]; ++t; }
        }
#pragma unroll
        for (int c = 0; c < 5; ++c) { acc[c] = 8.f * fo[c]; acc[5 + c] = sd[c]; }
        int t = 10, sc = 0;
        for (int p = 0; p < 10; ++p)
            for (int q = p; q < 10; ++q) {
                float v;
                if (q < 5) v = 8.f * fo[p] * fo[q];
                else if (p < 5) v = fo[p] * sd[q - 5];
                else { v = sdd[sc]; ++sc; }
                acc[t++] = v;
            }
    }
#pragma unroll 1
    for (int q = 0; q < 65; ++q) {
        float v = acc[q];
        for (int off = 32; off > 0; off >>= 1) v += __shfl_down(v, off, 64);
        acc[q] = v;
    }
    __shared__ float sh[4][65];
    int lane = threadIdx.x & 63, wid = threadIdx.x >> 6;
    if (lane == 0) {
        for (int q = 0; q < 65; ++q) sh[wid][q] = acc[q];
    }
    __syncthreads();
    if (threadIdx.x < 65) {
        float tot = sh[0][threadIdx.x] + sh[1][threadIdx.x] + sh[2][threadIdx.x] + sh[3][threadIdx.x];
        atomicAdd(&gacc[threadIdx.x], (double)tot);
    }
}

__global__ void k_gfinal(const double* __restrict__ gacc, const float* __restrict__ w2,
                         const float* __restrict__ b2, float* __restrict__ g2ab) {
    int o = threadIdx.x;
    if (o >= 128) return;
    double inv = 1.0 / (double)(BB * NN * 8);
    double Wr[10];
    for (int c = 0; c < 10; ++c) Wr[c] = (double)w2[o * 10 + c];
    double gm[10];
    for (int c = 0; c < 10; ++c) gm[c] = gacc[c] * inv;
    double b0 = (double)b2[o];
    double mean = b0;
    for (int c = 0; c < 10; ++c) mean += Wr[c] * gm[c];
    double e2 = b0 * b0 + 2.0 * b0 * (mean - b0);
    int t = 10;
    for (int p = 0; p < 10; ++p)
        for (int q = p; q < 10; ++q) {
            double G = gacc[t] * inv; ++t;
            double contrib = Wr[p] * Wr[q] * G;
            e2 += (p == q) ? contrib : 2.0 * contrib;
        }
    double var = e2 - mean * mean;
    double a = 1.0 / sqrt(var + 1e-5);
    g2ab[o] = (float)a;
    g2ab[128 + o] = (float)(-mean * a);
}

// graph conv + max over k + bn + relu (bn commutes with max since scale>0)
__global__ __launch_bounds__(256) void k_graphconv(const float* __restrict__ f5, const int* __restrict__ idxb,
                                                   const float* __restrict__ w2, const float* __restrict__ b2,
                                                   const float* __restrict__ g2ab, float* __restrict__ x0) {
    __shared__ float ws[1280], bs[128];
    __shared__ float fo_s[16][5], fnb_s[16][8][5];
    __shared__ int idxs[16][8];
    int b = blockIdx.x / 125, tile = blockIdx.x % 125;
    int nbase = tile * 16;
    int tid = threadIdx.x;
    for (int e = tid; e < 1280; e += 256) ws[e] = w2[e];
    if (tid < 128) bs[tid] = b2[tid];
    if (tid < 128) { int nn = tid >> 3, k = tid & 7; idxs[nn][k] = idxb[(b * NN + nbase + nn) * 8 + k]; }
    if (tid >= 128 && tid < 208) { int e = tid - 128; int nn = e / 5, c = e % 5; fo_s[nn][c] = f5[(b * 5 + c) * NN + nbase + nn]; }
    __syncthreads();
    for (int e = tid; e < 640; e += 256) {
        int nn = e / 40, r = e % 40, k = r / 5, c = r % 5;
        fnb_s[nn][k][c] = f5[(b * 5 + c) * NN + idxs[nn][k]];
    }
    __syncthreads();
    int nn = tid & 15, og = tid >> 4;
    float fo[5];
#pragma unroll
    for (int c = 0; c < 5; ++c) fo[c] = fo_s[nn][c];
    for (int oo = 0; oo < 8; ++oo) {
        int o = og * 8 + oo;
        float base = bs[o];
        float wn[5];
#pragma unroll
        for (int c = 0; c < 5; ++c) {
            float w1 = ws[o * 10 + c], w5 = ws[o * 10 + 5 + c];
            base += (w1 + w5) * fo[c];
            wn[c] = w5;
        }
        float mx = -1e30f;
        for (int k = 0; k < 8; ++k) {
            float v = base;
#pragma unroll
            for (int c = 0; c < 5; ++c) v -= wn[c] * fnb_s[nn][k][c];
            mx = fmaxf(mx, v);
        }
        float y = fmaxf(g2ab[o] * mx + g2ab[128 + o], 0.f);
        x0[(b * CH + o) * NN + nbase + nn] = y;
    }
}

// ---------------------------------------------------------------------------
// res-block support
// ---------------------------------------------------------------------------
__global__ void k_rowstats(const float* __restrict__ src, float* __restrict__ stats) {
    int row = blockIdx.x;  // b*128+c
    const float* p = src + row * NN;
    float s = 0.f, ss = 0.f;
    for (int n = threadIdx.x; n < NN; n += 256) { float v = p[n]; s += v; ss += v * v; }
    s = wred(s); ss = wred(ss);
    __shared__ float sh[8];
    int wid = threadIdx.x >> 6, lane = threadIdx.x & 63;
    if (lane == 0) { sh[wid] = s; sh[4 + wid] = ss; }
    __syncthreads();
    if (threadIdx.x == 0) {
        float S0 = sh[0] + sh[1] + sh[2] + sh[3];
        float SS = sh[4] + sh[5] + sh[6] + sh[7];
        float m = S0 / (float)NN;
        float var = SS / (float)NN - m * m;
        stats[row * 2] = m;
        stats[row * 2 + 1] = var;
    }
}

// instn + bn folded into per-(b,c) affine
__global__ void k_finalize(const float* __restrict__ stats, float* __restrict__ ab) {
    int c = threadIdx.x;
    if (c >= 128) return;
    float acc = 0.f;
    for (int b = 0; b < BB; ++b) { float var = stats[(b * CH + c) * 2 + 1]; acc += var / (var + 1e-5f); }
    float vc = acc / (float)BB;
    float sc = rsqrtf(vc + 1e-5f);
    for (int b = 0; b < BB; ++b) {
        float m = stats[(b * CH + c) * 2];
        float var = stats[(b * CH + c) * 2 + 1];
        float a = rsqrtf(var + 1e-5f) * sc;
        ab[(b * CH + c) * 2] = a;
        ab[(b * CH + c) * 2 + 1] = -m * a;
    }
}

__global__ void k_resadd(const float* __restrict__ Bm, const float* __restrict__ ab,
                         const float* __restrict__ x, float* __restrict__ y) {
    int i = blockIdx.x * 256 + threadIdx.x;
    if (i >= BB * CH * NN) return;
    int bc = i / NN;
    float v = ab[bc * 2] * Bm[i] + ab[bc * 2 + 1] + x[i];
    y[i] = fmaxf(v, 0.f);
}

// ---------------------------------------------------------------------------
// logit + weighted XwX
// ---------------------------------------------------------------------------
__global__ void k_logit(const float* __restrict__ x4, const float* __restrict__ wl,
                        const float* __restrict__ bl, float* __restrict__ outLogit) {
    int b = blockIdx.x >> 3, chunk = blockIdx.x & 7;
    int n = chunk * 256 + threadIdx.x;
    if (n >= NN) return;
    float acc = 0.f;
    for (int c = 0; c < CH; ++c) acc += wl[c] * x4[(b * CH + c) * NN + n];
    outLogit[b * NN + n] = acc + bl[0];
}

__global__ __launch_bounds__(256) void k_xwx(const float* __restrict__ logit, const float* __restrict__ x_in,
                                             float* __restrict__ XwX) {
    int b = blockIdx.x;
    int tid = threadIdx.x;
    float a[45];
#pragma unroll
    for (int q = 0; q < 45; ++q) a[q] = 0.f;
    for (int n = tid; n < NN; n += 256) {
        float lg = logit[b * NN + n];
        float w = fmaxf(tanhf(lg), 0.f);
        const float* xp = x_in + (b * NN + n) * 4;
        float px = xp[0], py = xp[1], z = xp[2], wq = xp[3];
        float X9[9] = {z * px, z * py, z, wq * px, wq * py, wq, px, py, 1.f};
        int t = 0;
#pragma unroll
        for (int p = 0; p < 9; ++p) {
            float wp = w * X9[p];
#pragma unroll
            for (int q = p; q < 9; ++q) { a[t] += wp * X9[q]; ++t; }
        }
    }
#pragma unroll 1
    for (int q = 0; q < 45; ++q) {
        float v = a[q];
        for (int off = 32; off > 0; off >>= 1) v += __shfl_down(v, off, 64);
        a[q] = v;
    }
    __shared__ float sh[4][45];
    int lane = tid & 63, wid = tid >> 6;
    if (lane == 0) {
        for (int q = 0; q < 45; ++q) sh[wid][q] = a[q];
    }
    __syncthreads();
    if (tid < 45) XwX[b * 45 + tid] = sh[0][tid] + sh[1][tid] + sh[2][tid] + sh[3][tid];
}

// ---------------------------------------------------------------------------
// 9x9 symmetric eigensolver — faithful LAPACK ssyevd (f32) emulation:
// ssytd2 (lower) + ssteqr + sormtr back-transform, f32 LAPACK constants,
// LAPACK >=3.10 slartg (c >= 0).  Verified passing in r3 — do not touch.
// ---------------------------------------------------------------------------
__device__ inline float slapy2_f(float x, float y) {
    float xa = fabsf(x), ya = fabsf(y);
    float w = fmaxf(xa, ya), z = fminf(xa, ya);
    if (z == 0.f) return w;
    float q = z / w;
    return w * sqrtf(1.f + q * q);
}

__device__ inline void slartg_f(float f, float g, float& c, float& s, float& r) {
    if (g == 0.f) { c = 1.f; s = 0.f; r = f; }
    else if (f == 0.f) { c = 0.f; s = (g > 0.f ? 1.f : -1.f); r = fabsf(g); }
    else {
        float d = sqrtf(f * f + g * g);
        c = fabsf(f) / d;
        r = (f >= 0.f) ? d : -d;
        s = g / r;
    }
}

__device__ void slaev2_f(float a, float b, float c, float& rt1, float& rt2, float& cs1, float& sn1) {
    float sm = a + c, df = a - c;
    float adf = fabsf(df), tb = b + b, ab = fabsf(tb);
    float acmx, acmn;
    if (fabsf(a) > fabsf(c)) { acmx = a; acmn = c; } else { acmx = c; acmn = a; }
    float rt;
    if (adf > ab) { float q = ab / adf; rt = adf * sqrtf(1.f + q * q); }
    else if (adf < ab) { float q = adf / ab; rt = ab * sqrtf(1.f + q * q); }
    else rt = ab * sqrtf(2.f);
    int sgn1;
    if (sm < 0.f) { rt1 = 0.5f * (sm - rt); sgn1 = -1; rt2 = (acmx / rt1) * acmn - (b / rt1) * b; }
    else if (sm > 0.f) { rt1 = 0.5f * (sm + rt); sgn1 = 1; rt2 = (acmx / rt1) * acmn - (b / rt1) * b; }
    else { rt1 = 0.5f * rt; rt2 = -0.5f * rt; sgn1 = 1; }
    float cs; int sgn2;
    if (df >= 0.f) { cs = df + rt; sgn2 = 1; } else { cs = df - rt; sgn2 = -1; }
    float acs = fabsf(cs);
    if (acs > ab) {
        float ct = -tb / cs;
        sn1 = 1.f / sqrtf(1.f + ct * ct);
        cs1 = ct * sn1;
    } else {
        if (ab == 0.f) { cs1 = 1.f; sn1 = 0.f; }
        else { float tn = -cs / tb; cs1 = 1.f / sqrtf(1.f + tn * tn); sn1 = tn * cs1; }
    }
    if (sgn1 == sgn2) { float tn = cs1; cs1 = -sn1; sn1 = tn; }
}

__global__ __launch_bounds__(64) void k_eigh(const float* __restrict__ XwX, float* __restrict__ out_e) {
    __shared__ float shA[16 * 81];
    __shared__ float shZ[16 * 81];
    int bb = threadIdx.x;
    if (bb >= 16) return;
    float* Am = shA + bb * 81;
    float* Zm = shZ + bb * 81;
#define AA(i, j) Am[(i) * 9 + (j)]
#define ZZ(i, j) Zm[(i) * 9 + (j)]
    {
        const float* src = XwX + bb * 45;
        int t = 0;
        for (int p = 0; p < 9; ++p)
            for (int q = p; q < 9; ++q) { float v = src[t++]; AA(p, q) = v; AA(q, p) = v; }
    }
    float d[9], e[9], tau[9];
    for (int i = 0; i < 8; ++i) {
        float alpha = AA(i + 1, i);
        float xn2 = 0.f;
        for (int j = i + 2; j < 9; ++j) xn2 += AA(j, i) * AA(j, i);
        float taui;
        if (xn2 == 0.f) { taui = 0.f; e[i] = alpha; }
        else {
            float xnorm = sqrtf(xn2);
            float beta = slapy2_f(alpha, xnorm);
            beta = (alpha >= 0.f) ? -beta : beta;
            taui = (beta - alpha) / beta;
            float scl = 1.f / (alpha - beta);
            for (int j = i + 2; j < 9; ++j) AA(j, i) *= scl;
            e[i] = beta;
            float p[9], w[9];
            for (int j = i + 1; j < 9; ++j) {
                float acc = AA(j, i + 1);
                for (int k2 = i + 2; k2 < 9; ++k2) acc += AA(j, k2) * AA(k2, i);
                p[j] = taui * acc;
            }
            float dot = p[i + 1];
            for (int j = i + 2; j < 9; ++j) dot += p[j] * AA(j, i);
            float alpha2 = -0.5f * taui * dot;
            w[i + 1] = p[i + 1] + alpha2;
            for (int j = i + 2; j < 9; ++j) w[j] = p[j] + alpha2 * AA(j, i);
            for (int j = i + 1; j < 9; ++j) {
                float vj = (j == i + 1) ? 1.f : AA(j, i);
                for (int k2 = i + 1; k2 < 9; ++k2) {
                    float vk = (k2 == i + 1) ? 1.f : AA(k2, i);
                    AA(j, k2) -= vj * w[k2] + w[j] * vk;
                }
            }
        }
        tau[i] = taui;
    }
    for (int i = 0; i < 9; ++i) d[i] = AA(i, i);
    for (int i = 0; i < 81; ++i) Zm[i] = 0.f;
    for (int i = 0; i < 9; ++i) ZZ(i, i) = 1.f;
    const float eps = 5.9604645e-08f;
    const float eps2 = 3.5527137e-15f;
    const float safmin = 1.17549435e-38f;
    const int n = 9;
    int nmaxit = n * 30, jtot = 0;
    int l1 = 0;
    while (l1 <= n - 1) {
        if (l1 > 0) e[l1 - 1] = 0.f;
        int m = n - 1;
        for (int mm = l1; mm <= n - 2; ++mm) {
            float tst = fabsf(e[mm]);
            if (tst == 0.f) { m = mm; break; }
            if (tst <= (sqrtf(fabsf(d[mm])) * sqrtf(fabsf(d[mm + 1]))) * eps) { e[mm] = 0.f; m = mm; break; }
        }
        int l = l1, lsv = l, lend = m, lendsv = lend;
        l1 = m + 1;
        if (lend == l) continue;
        if (fabsf(d[lend]) < fabsf(d[l])) { lend = lsv; l = lendsv; }
        if (lend > l) {
            for (;;) {
                int m2 = lend;
                if (l != lend) {
                    for (int mm = l; mm <= lend - 1; ++mm) {
                        float tst = e[mm] * e[mm];
                        if (tst <= (eps2 * fabsf(d[mm])) * fabsf(d[mm + 1]) + safmin) { m2 = mm; break; }
                    }
                }
                if (m2 < lend) e[m2] = 0.f;
                float p = d[l];
                if (m2 == l) { d[l] = p; ++l; if (l <= lend) continue; else break; }
                if (m2 == l + 1) {
                    float rt1, rt2, c, s;
                    slaev2_f(d[l], e[l], d[l + 1], rt1, rt2, c, s);
                    for (int r2 = 0; r2 < 9; ++r2) {
                        float tmp = ZZ(r2, l + 1);
                        ZZ(r2, l + 1) = c * tmp - s * ZZ(r2, l);
                        ZZ(r2, l) = s * tmp + c * ZZ(r2, l);
                    }
                    d[l] = rt1; d[l + 1] = rt2; e[l] = 0.f; l += 2;
                    if (l <= lend) continue; else break;
                }
                if (jtot == nmaxit) break;
                ++jtot;
                float g = (d[l + 1] - p) / (2.f * e[l]);
                float r = slapy2_f(g, 1.f);
                g = d[m2] - p + e[l] / (g + (g >= 0.f ? fabsf(r) : -fabsf(r)));
                float s = 1.f, c = 1.f;
                p = 0.f;
                float csv[9], snv[9];
                for (int i = m2 - 1; i >= l; --i) {
                    float f = s * e[i], bq = c * e[i];
                    slartg_f(g, f, c, s, r);
                    if (i != m2 - 1) e[i + 1] = r;
                    g = d[i + 1] - p;
                    r = (d[i] - g) * s + 2.f * c * bq;
                    p = s * r;
                    d[i + 1] = g + p;
                    g = c * r - bq;
                    csv[i] = c; snv[i] = -s;
                }
                for (int jj = m2 - 1; jj >= l; --jj) {
                    float cj = csv[jj], sj = snv[jj];
                    for (int r2 = 0; r2 < 9; ++r2) {
                        float tmp = ZZ(r2, jj + 1);
                        ZZ(r2, jj + 1) = cj * tmp - sj * ZZ(r2, jj);
                        ZZ(r2, jj) = sj * tmp + cj * ZZ(r2, jj);
                    }
                }
                d[l] -= p; e[l] = g;
            }
        } else {
            for (;;) {
                int m2 = lend;
                if (l != lend) {
                    for (int mm = l; mm >= lend + 1; --mm) {
                        float tst = e[mm - 1] * e[mm - 1];
                        if (tst <= (eps2 * fabsf(d[mm])) * fabsf(d[mm - 1]) + safmin) { m2 = mm; break; }
                    }
                }
                if (m2 > lend) e[m2 - 1] = 0.f;
                float p = d[l];
                if (m2 == l) { d[l] = p; --l; if (l >= lend) continue; else break; }
                if (m2 == l - 1) {
                    float rt1, rt2, c, s;
                    slaev2_f(d[l - 1], e[l - 1], d[l], rt1, rt2, c, s);
                    for (int r2 = 0; r2 < 9; ++r2) {
                        float tmp = ZZ(r2, l);
                        ZZ(r2, l) = c * tmp - s * ZZ(r2, l - 1);
                        ZZ(r2, l - 1) = s * tmp + c * ZZ(r2, l - 1);
                    }
                    d[l - 1] = rt1; d[l] = rt2; e[l - 1] = 0.f; l -= 2;
                    if (l >= lend) continue; else break;
                }
                if (jtot == nmaxit) break;
                ++jtot;
                float g = (d[l - 1] - p) / (2.f * e[l - 1]);
                float r = slapy2_f(g, 1.f);
                g = d[m2] - p + e[l - 1] / (g + (g >= 0.f ? fabsf(r) : -fabsf(r)));
                float s = 1.f, c = 1.f;
                p = 0.f;
                float csv[9], snv[9];
                for (int i = m2; i <= l - 1; ++i) {
                    float f = s * e[i], bq = c * e[i];
                    slartg_f(g, f, c, s, r);
                    if (i != m2) e[i - 1] = r;
                    g = d[i] - p;
                    r = (d[i + 1] - g) * s + 2.f * c * bq;
                    p = s * r;
                    d[i] = g + p;
                    g = c * r - bq;
                    csv[i] = c; snv[i] = s;
                }
                for (int jj = m2; jj <= l - 1; ++jj) {
                    float cj = csv[jj], sj = snv[jj];
                    for (int r2 = 0; r2 < 9; ++r2) {
                        float tmp = ZZ(r2, jj + 1);
                        ZZ(r2, jj + 1) = cj * tmp - sj * ZZ(r2, jj);
                        ZZ(r2, jj) = sj * tmp + cj * ZZ(r2, jj);
                    }
                }
                d[l] -= p; e[l - 1] = g;
            }
        }
    }
    for (int ii = 1; ii < 9; ++ii) {
        int i = ii - 1, kk = i;
        float p = d[i];
        for (int j = ii; j < 9; ++j)
            if (d[j] < p) { kk = j; p = d[j]; }
        if (kk != i) {
            d[kk] = d[i]; d[i] = p;
            for (int r2 = 0; r2 < 9; ++r2) { float tmp = ZZ(r2, i); ZZ(r2, i) = ZZ(r2, kk); ZZ(r2, kk) = tmp; }
        }
    }
    float v0[9];
    for (int r2 = 0; r2 < 9; ++r2) v0[r2] = ZZ(r2, 0);
    for (int i = 7; i >= 0; --i) {
        float ti = tau[i];
        if (ti == 0.f) continue;
        float dot = v0[i + 1];
        for (int j = i + 2; j < 9; ++j) dot += AA(j, i) * v0[j];
        dot *= ti;
        v0[i + 1] -= dot;
        for (int j = i + 2; j < 9; ++j) v0[j] -= AA(j, i) * dot;
    }
    float nrm = 0.f;
    for (int r2 = 0; r2 < 9; ++r2) nrm += v0[r2] * v0[r2];
    nrm = sqrtf(nrm);
    for (int r2 = 0; r2 < 9; ++r2) out_e[bb * 9 + r2] = v0[r2] / nrm;
#undef AA
#undef ZZ
}

// ---------------------------------------------------------------------------
// launch
// ---------------------------------------------------------------------------
extern "C" void kernel_launch(void* const* d_in, const int* in_sizes, int n_in,
                              void* d_out, int out_size, void* d_ws, size_t ws_size,
                              hipStream_t stream) {
    const float* data = (const float*)d_in[0];
    const float* x_in = (const float*)d_in[1];
    const float* w1a = (const float*)d_in[2];
    const float* b1a = (const float*)d_in[3];
    const float* w1b = (const float*)d_in[4];
    const float* b1b = (const float*)d_in[5];
    const float* w2 = (const float*)d_in[6];
    const float* b2 = (const float*)d_in[7];
    const float* res_wa = (const float*)d_in[8];
    const float* res_ba = (const float*)d_in[9];
    const float* res_wb = (const float*)d_in[10];
    const float* res_bb = (const float*)d_in[11];
    const float* wl = (const float*)d_in[12];
    const float* bl = (const float*)d_in[13];
    float* out = (float*)d_out;

    // workspace layout
    double* gacc = (double*)d_ws;                       // 65 doubles (needs memset)
    float* xwx = (float*)((char*)d_ws + 1024);          // 16*45 floats
    float* fbase = (float*)((char*)d_ws + 8192);
    float* big0 = fbase;
    float* big1 = big0 + BB * CH * NN;
    float* big2 = big1 + BB * CH * NN;
    float* tbuf = big2 + BB * CH * NN;
    float* f5 = tbuf + BB * 4 * NN;
    float* invn = f5 + BB * 5 * NN;
    float* Sv = invn + BB * NN;
    int* idxb = (int*)(Sv + BB * CH);
    float* chAB = (float*)(idxb + BB * NN * 8);
    float* stA = chAB + 256;
    float* abA = stA + BB * CH * 2;
    float* stB = abA + BB * CH * 2;
    float* abB = stB + BB * CH * 2;
    float* g2ab = abB + BB * CH * 2;
    // kNN partials live in big2 (free until the res-blocks): 2.048M floats +
    // 2.048M ints = exactly BB*CH*NN floats.
    float* knn_pd = big2;
    int* knn_pj = (int*)(big2 + BB * NN * JCH * 8);

    hipMemsetAsync(d_ws, 0, 1024, stream);

    k_build_t<<<500, 256, 0, stream>>>(data, tbuf);
    k_conv1<<<16000, 256, 0, stream>>>(tbuf, w1a, b1a, big0);
    k_chanstats<<<128, 256, 0, stream>>>(big0, chAB);
    k_gemm<<<dim3(2, 512), 256, 0, stream>>>(big0, w1b, b1b, big1, chAB, 1);  // h2 in big1
    k_invn<<<128, 256, 0, stream>>>(big1, invn);
    k_S<<<2048, 256, 0, stream>>>(big1, invn, Sv);
    k_Df<<<128, 256, 0, stream>>>(big1, invn, Sv, tbuf, out, f5);
    k_knn_part<<<dim3(JCH, 8, BB), 256, 0, stream>>>(f5, knn_pd, knn_pj);
    k_knn_merge<<<125, 256, 0, stream>>>(knn_pd, knn_pj, idxb);
    k_gstats<<<125, 256, 0, stream>>>(f5, idxb, gacc);
    k_gfinal<<<1, 128, 0, stream>>>(gacc, w2, b2, g2ab);
    k_graphconv<<<2000, 256, 0, stream>>>(f5, idxb, w2, b2, g2ab, big0);  // x0 in big0

    float* xb = big0;
    float* hb = big1;
    for (int i = 0; i < 4; ++i) {
        k_gemm<<<dim3(2, 512), 256, 0, stream>>>(xb, res_wa + i * CH * CH, res_ba + i * CH, hb, nullptr, 0);
        k_rowstats<<<2048, 256, 0, stream>>>(hb, stA);
        k_finalize<<<1, 128, 0, stream>>>(stA, abA);
        k_gemm<<<dim3(2, 512), 256, 0, stream>>>(hb, res_wb + i * CH * CH, res_bb + i * CH, big2, abA, 2);
        k_rowstats<<<2048, 256, 0, stream>>>(big2, stB);
        k_finalize<<<1, 128, 0, stream>>>(stB, abB);
        k_resadd<<<16000, 256, 0, stream>>>(big2, abB, xb, hb);
        float* tmp = xb; xb = hb; hb = tmp;
    }

    k_logit<<<128, 256, 0, stream>>>(xb, wl, bl, out + BB * NN);
    k_xwx<<<16, 256, 0, stream>>>(out + BB * NN, x_in, xwx);
    k_eigh<<<1, 64, 0, stream>>>(xwx, out + 2 * BB * NN);
}

// Round 5
// 942.575 us; speedup vs baseline: 1.3105x; 1.1251x over previous
//
#include <hip/hip_runtime.h>
#include <math.h>

#define BB 16
#define NN 2000
#define CH 128
#define KNN 8
#define JCH 8
#define JSZ 250  // NN / JCH

// ---------------------------------------------------------------------------
// helpers
// ---------------------------------------------------------------------------
__device__ inline float wred(float v) {
    for (int off = 32; off > 0; off >>= 1) v += __shfl_down(v, off, 64);
    return v;
}

// ---------------------------------------------------------------------------
// stage 0: t[b,c,n] = data[b,0,n,c]
// ---------------------------------------------------------------------------
__global__ void k_build_t(const float* __restrict__ data, float* __restrict__ t) {
    int i = blockIdx.x * 256 + threadIdx.x;
    if (i >= BB * 4 * NN) return;
    int n = i % NN;
    int c = (i / NN) & 3;
    int b = i / (4 * NN);
    t[i] = data[(b * NN + n) * 4 + c];
}

// conv1: c1[b,o,n] = sum_c w1a[o,c]*t[b,c,n] + b1a[o]
__global__ void k_conv1(const float* __restrict__ t, const float* __restrict__ w1a,
                        const float* __restrict__ b1a, float* __restrict__ c1) {
    int i = blockIdx.x * 256 + threadIdx.x;  // (b*128+o)*N+n
    if (i >= BB * CH * NN) return;
    int n = i % NN;
    int rest = i / NN;
    int o = rest & 127;
    int b = rest >> 7;
    float acc = b1a[o];
    for (int c = 0; c < 4; ++c) acc += w1a[o * 4 + c] * t[(b * 4 + c) * NN + n];
    c1[i] = acc;
}

// per-channel bn stats over (b,n): 128 blocks
__global__ void k_chanstats(const float* __restrict__ src, float* __restrict__ chAB) {
    int o = blockIdx.x;
    int tid = threadIdx.x;
    float s = 0.f, ss = 0.f;
    for (int b = 0; b < BB; ++b) {
        const float* p = src + (b * CH + o) * NN;
        for (int n = tid; n < NN; n += 256) { float v = p[n]; s += v; ss += v * v; }
    }
    s = wred(s); ss = wred(ss);
    __shared__ float sh[8];
    int wid = tid >> 6, lane = tid & 63;
    if (lane == 0) { sh[wid] = s; sh[4 + wid] = ss; }
    __syncthreads();
    if (tid == 0) {
        float S0 = sh[0] + sh[1] + sh[2] + sh[3];
        float SS = sh[4] + sh[5] + sh[6] + sh[7];
        float m = S0 / (float)(BB * NN);
        float var = SS / (float)(BB * NN) - m * m;
        float a = rsqrtf(var + 1e-5f);
        chAB[o] = a;
        chAB[CH + o] = -m * a;
    }
}

// ---------------------------------------------------------------------------
// generic 128x128 GEMM over columns (b,n), with input transform.
// mode 0: raw; mode 1: relu(chAB[j]*x + chAB[128+j]); mode 2: relu(ab[(b*128+j)*2]*x + ab[..+1])
// grid: (2, B*32), block 256.  tile: 64 o x 64 n.
// Ws padded to 68 floats/row (272 B, 16 B aligned) so fragment reads are
// ds_read_b128.  FMA accumulation order is IDENTICAL to the r3 baseline —
// do not reorder (absmax margin 0.34/0.4225 depends on it).
// ---------------------------------------------------------------------------
__global__ __launch_bounds__(256) void k_gemm(const float* __restrict__ X, const float* __restrict__ W,
                                              const float* __restrict__ bias, float* __restrict__ Y,
                                              const float* __restrict__ ab, int mode) {
    int ot = blockIdx.x, by = blockIdx.y;
    int b = by >> 5, nt = by & 31;
    int n0 = nt * 64, o0 = ot * 64;
    int tid = threadIdx.x;
    int tx = tid & 15, ty = tid >> 4;
    __shared__ float Xs[32][64];
    __shared__ float Ws[32][68];
    float acc[4][4] = {};
    for (int jc = 0; jc < 4; ++jc) {
        for (int q = 0; q < 8; ++q) {
            int e = q * 256 + tid;
            int jj = e >> 6, nn = e & 63;
            int j = jc * 32 + jj, n = n0 + nn;
            float v = 0.f;
            if (n < NN) {
                v = X[(b * CH + j) * NN + n];
                if (mode == 1) v = fmaxf(ab[j] * v + ab[CH + j], 0.f);
                else if (mode == 2) { int bc = b * CH + j; v = fmaxf(ab[bc * 2] * v + ab[bc * 2 + 1], 0.f); }
            }
            Xs[jj][nn] = v;
        }
        for (int q = 0; q < 8; ++q) {
            int e = q * 256 + tid;
            int jj = e & 31, oo = e >> 5;
            Ws[jj][oo] = W[(o0 + oo) * CH + jc * 32 + jj];
        }
        __syncthreads();
        for (int jj = 0; jj < 32; ++jj) {
            float4 wv = *(const float4*)&Ws[jj][ty * 4];
            float4 xv = *(const float4*)&Xs[jj][tx * 4];
            float wva[4] = {wv.x, wv.y, wv.z, wv.w};
            float xva[4] = {xv.x, xv.y, xv.z, xv.w};
#pragma unroll
            for (int a = 0; a < 4; ++a)
#pragma unroll
                for (int bq = 0; bq < 4; ++bq) acc[a][bq] += wva[a] * xva[bq];
        }
        __syncthreads();
    }
    for (int a = 0; a < 4; ++a) {
        int o = o0 + ty * 4 + a;
        float bi = bias[o];
        for (int q = 0; q < 4; ++q) {
            int n = n0 + tx * 4 + q;
            if (n < NN) Y[(b * CH + o) * NN + n] = acc[a][q] + bi;
        }
    }
}

// ---------------------------------------------------------------------------
// stage 1 tail: channel-norm, S, D, f5
// ---------------------------------------------------------------------------
__global__ void k_invn(const float* __restrict__ h2, float* __restrict__ invn) {
    int b = blockIdx.x >> 3, chunk = blockIdx.x & 7;
    int n = chunk * 256 + threadIdx.x;
    if (n >= NN) return;
    float acc = 0.f;
    for (int c = 0; c < CH; ++c) { float v = h2[(b * CH + c) * NN + n]; acc += v * v; }
    invn[b * NN + n] = 1.f / (sqrtf(acc) + 1e-5f);
}

__global__ void k_S(const float* __restrict__ h2, const float* __restrict__ invn, float* __restrict__ Sv) {
    int row = blockIdx.x;  // b*128+c
    int b = row >> 7;
    const float* p = h2 + row * NN;
    const float* iv = invn + b * NN;
    float s = 0.f;
    for (int n = threadIdx.x; n < NN; n += 256) s += p[n] * iv[n];
    s = wred(s);
    __shared__ float sh[4];
    int wid = threadIdx.x >> 6, lane = threadIdx.x & 63;
    if (lane == 0) sh[wid] = s;
    __syncthreads();
    if (threadIdx.x == 0) Sv[row] = sh[0] + sh[1] + sh[2] + sh[3];
}

__global__ void k_Df(const float* __restrict__ h2, const float* __restrict__ invn,
                     const float* __restrict__ Sv, const float* __restrict__ t,
                     float* __restrict__ outD, float* __restrict__ f5) {
    int b = blockIdx.x >> 3, chunk = blockIdx.x & 7;
    int n = chunk * 256 + threadIdx.x;
    if (n >= NN) return;
    float acc = 0.f;
    for (int c = 0; c < CH; ++c) acc += h2[(b * CH + c) * NN + n] * Sv[b * CH + c];
    float Ar = acc * invn[b * NN + n];
    float Dv = (Ar - 1.0f) / (float)NN;
    outD[b * NN + n] = Dv;
    for (int c = 0; c < 4; ++c) f5[(b * 5 + c) * NN + n] = t[(b * 4 + c) * NN + n];
    f5[(b * 5 + 4) * NN + n] = fmaxf(tanhf(Dv), 0.f);
}

// ---------------------------------------------------------------------------
// kNN stage A: per (b, i, j-chunk) partial top-8 over 250 candidates.
// ---------------------------------------------------------------------------
__global__ __launch_bounds__(256) void k_knn_part(const float* __restrict__ f5,
                                                  float* __restrict__ pd, int* __restrict__ pj) {
    __shared__ float fs[5][JSZ];
    int jc = blockIdx.x, ic = blockIdx.y, b = blockIdx.z;
    int j0 = jc * JSZ;
    int tid = threadIdx.x;
    for (int e = tid; e < 5 * JSZ; e += 256) {
        int c = e / JSZ, jj = e - c * JSZ;
        fs[c][jj] = f5[(b * 5 + c) * NN + j0 + jj];
    }
    __syncthreads();
    int i = ic * 256 + tid;
    if (i >= NN) return;
    float fi0 = f5[(b * 5 + 0) * NN + i], fi1 = f5[(b * 5 + 1) * NN + i],
          fi2 = f5[(b * 5 + 2) * NN + i], fi3 = f5[(b * 5 + 3) * NN + i],
          fi4 = f5[(b * 5 + 4) * NN + i];
    float bd[8]; int bj[8];
    for (int q = 0; q < 8; ++q) { bd[q] = 1e30f; bj[q] = 0x7fffffff; }
    float worst = 1e30f;
    for (int jj = 0; jj < JSZ; ++jj) {
        int j = j0 + jj;
        float d0 = fi0 - fs[0][jj], d1 = fi1 - fs[1][jj], d2 = fi2 - fs[2][jj];
        float d3 = fi3 - fs[3][jj], d4 = fi4 - fs[4][jj];
        float d = d0 * d0 + d1 * d1 + d2 * d2 + d3 * d3 + d4 * d4;
        if (j == i) continue;
        if (d < worst) {
            int pos = 7;
            while (pos > 0 && d < bd[pos - 1]) { bd[pos] = bd[pos - 1]; bj[pos] = bj[pos - 1]; --pos; }
            bd[pos] = d; bj[pos] = j;
            worst = bd[7];
        }
    }
    long base = ((long)(b * NN + i) * JCH + jc) * 8;
    for (int q = 0; q < 8; ++q) { pd[base + q] = bd[q]; pj[base + q] = bj[q]; }
}

// kNN stage B: 8-way merge of sorted partial lists.
__global__ __launch_bounds__(256) void k_knn_merge(const float* __restrict__ pd, const int* __restrict__ pj,
                                                   int* __restrict__ idxb) {
    int s = blockIdx.x * 256 + threadIdx.x;  // b*NN + i
    if (s >= BB * NN) return;
    const float* dl = pd + (long)s * JCH * 8;
    const int* jl = pj + (long)s * JCH * 8;
    int ptr[JCH];
#pragma unroll
    for (int c = 0; c < JCH; ++c) ptr[c] = 0;
    for (int q = 0; q < 8; ++q) {
        float best = 1e38f; int bestj = 0x7fffffff; int bc = 0;
#pragma unroll
        for (int c = 0; c < JCH; ++c) {
            if (ptr[c] < 8) {
                float d = dl[c * 8 + ptr[c]];
                int j = jl[c * 8 + ptr[c]];
                if (d < best || (d == best && j < bestj)) { best = d; bestj = j; bc = c; }
            }
        }
        idxb[s * 8 + q] = bestj;
        ++ptr[bc];
    }
}

// ---------------------------------------------------------------------------
// graph-feature statistics: 10 means + 55 second moments (f64 accumulators)
// ---------------------------------------------------------------------------
__global__ __launch_bounds__(256) void k_gstats(const float* __restrict__ f5, const int* __restrict__ idxb,
                                                double* __restrict__ gacc) {
    int s = blockIdx.x * 256 + threadIdx.x;
    float acc[65];
#pragma unroll
    for (int q = 0; q < 65; ++q) acc[q] = 0.f;
    if (s < BB * NN) {
        int b = s / NN, n = s - b * NN;
        float fo[5];
#pragma unroll
        for (int c = 0; c < 5; ++c) fo[c] = f5[(b * 5 + c) * NN + n];
        float sd[5] = {0, 0, 0, 0, 0};
        float sdd[15];
#pragma unroll
        for (int q = 0; q < 15; ++q) sdd[q] = 0.f;
        for (int k = 0; k < 8; ++k) {
            int j = idxb[s * 8 + k];
            float df[5];
#pragma unroll
            for (int c = 0; c < 5; ++c) df[c] = fo[c] - f5[(b * 5 + c) * NN + j];
#pragma unroll
            for (int c = 0; c < 5; ++c) sd[c] += df[c];
            int t = 0;
#pragma unroll
            for (int c = 0; c < 5; ++c)
#pragma unroll
                for (int d2 = c; d2 < 5; ++d2) { sdd[t] += df[c] * df[d2]; ++t; }
        }
#pragma unroll
        for (int c = 0; c < 5; ++c) { acc[c] = 8.f * fo[c]; acc[5 + c] = sd[c]; }
        int t = 10, sc = 0;
        for (int p = 0; p < 10; ++p)
            for (int q = p; q < 10; ++q) {
                float v;
                if (q < 5) v = 8.f * fo[p] * fo[q];
                else if (p < 5) v = fo[p] * sd[q - 5];
                else { v = sdd[sc]; ++sc; }
                acc[t++] = v;
            }
    }
#pragma unroll 1
    for (int q = 0; q < 65; ++q) {
        float v = acc[q];
        for (int off = 32; off > 0; off >>= 1) v += __shfl_down(v, off, 64);
        acc[q] = v;
    }
    __shared__ float sh[4][65];
    int lane = threadIdx.x & 63, wid = threadIdx.x >> 6;
    if (lane == 0) {
        for (int q = 0; q < 65; ++q) sh[wid][q] = acc[q];
    }
    __syncthreads();
    if (threadIdx.x < 65) {
        float tot = sh[0][threadIdx.x] + sh[1][threadIdx.x] + sh[2][threadIdx.x] + sh[3][threadIdx.x];
        atomicAdd(&gacc[threadIdx.x], (double)tot);
    }
}

__global__ void k_gfinal(const double* __restrict__ gacc, const float* __restrict__ w2,
                         const float* __restrict__ b2, float* __restrict__ g2ab) {
    int o = threadIdx.x;
    if (o >= 128) return;
    double inv = 1.0 / (double)(BB * NN * 8);
    double Wr[10];
    for (int c = 0; c < 10; ++c) Wr[c] = (double)w2[o * 10 + c];
    double gm[10];
    for (int c = 0; c < 10; ++c) gm[c] = gacc[c] * inv;
    double b0 = (double)b2[o];
    double mean = b0;
    for (int c = 0; c < 10; ++c) mean += Wr[c] * gm[c];
    double e2 = b0 * b0 + 2.0 * b0 * (mean - b0);
    int t = 10;
    for (int p = 0; p < 10; ++p)
        for (int q = p; q < 10; ++q) {
            double G = gacc[t] * inv; ++t;
            double contrib = Wr[p] * Wr[q] * G;
            e2 += (p == q) ? contrib : 2.0 * contrib;
        }
    double var = e2 - mean * mean;
    double a = 1.0 / sqrt(var + 1e-5);
    g2ab[o] = (float)a;
    g2ab[128 + o] = (float)(-mean * a);
}

// graph conv + max over k + bn + relu (bn commutes with max since scale>0)
__global__ __launch_bounds__(256) void k_graphconv(const float* __restrict__ f5, const int* __restrict__ idxb,
                                                   const float* __restrict__ w2, const float* __restrict__ b2,
                                                   const float* __restrict__ g2ab, float* __restrict__ x0) {
    __shared__ float ws[1280], bs[128];
    __shared__ float fo_s[16][5], fnb_s[16][8][5];
    __shared__ int idxs[16][8];
    int b = blockIdx.x / 125, tile = blockIdx.x % 125;
    int nbase = tile * 16;
    int tid = threadIdx.x;
    for (int e = tid; e < 1280; e += 256) ws[e] = w2[e];
    if (tid < 128) bs[tid] = b2[tid];
    if (tid < 128) { int nn = tid >> 3, k = tid & 7; idxs[nn][k] = idxb[(b * NN + nbase + nn) * 8 + k]; }
    if (tid >= 128 && tid < 208) { int e = tid - 128; int nn = e / 5, c = e % 5; fo_s[nn][c] = f5[(b * 5 + c) * NN + nbase + nn]; }
    __syncthreads();
    for (int e = tid; e < 640; e += 256) {
        int nn = e / 40, r = e % 40, k = r / 5, c = r % 5;
        fnb_s[nn][k][c] = f5[(b * 5 + c) * NN + idxs[nn][k]];
    }
    __syncthreads();
    int nn = tid & 15, og = tid >> 4;
    float fo[5];
#pragma unroll
    for (int c = 0; c < 5; ++c) fo[c] = fo_s[nn][c];
    for (int oo = 0; oo < 8; ++oo) {
        int o = og * 8 + oo;
        float base = bs[o];
        float wn[5];
#pragma unroll
        for (int c = 0; c < 5; ++c) {
            float w1 = ws[o * 10 + c], w5 = ws[o * 10 + 5 + c];
            base += (w1 + w5) * fo[c];
            wn[c] = w5;
        }
        float mx = -1e30f;
        for (int k = 0; k < 8; ++k) {
            float v = base;
#pragma unroll
            for (int c = 0; c < 5; ++c) v -= wn[c] * fnb_s[nn][k][c];
            mx = fmaxf(mx, v);
        }
        float y = fmaxf(g2ab[o] * mx + g2ab[128 + o], 0.f);
        x0[(b * CH + o) * NN + nbase + nn] = y;
    }
}

// ---------------------------------------------------------------------------
// res-block support
// ---------------------------------------------------------------------------
__global__ void k_rowstats(const float* __restrict__ src, float* __restrict__ stats) {
    int row = blockIdx.x;  // b*128+c
    const float* p = src + row * NN;
    float s = 0.f, ss = 0.f;
    for (int n = threadIdx.x; n < NN; n += 256) { float v = p[n]; s += v; ss += v * v; }
    s = wred(s); ss = wred(ss);
    __shared__ float sh[8];
    int wid = threadIdx.x >> 6, lane = threadIdx.x & 63;
    if (lane == 0) { sh[wid] = s; sh[4 + wid] = ss; }
    __syncthreads();
    if (threadIdx.x == 0) {
        float S0 = sh[0] + sh[1] + sh[2] + sh[3];
        float SS = sh[4] + sh[5] + sh[6] + sh[7];
        float m = S0 / (float)NN;
        float var = SS / (float)NN - m * m;
        stats[row * 2] = m;
        stats[row * 2 + 1] = var;
    }
}

// instn + bn folded into per-(b,c) affine
__global__ void k_finalize(const float* __restrict__ stats, float* __restrict__ ab) {
    int c = threadIdx.x;
    if (c >= 128) return;
    float acc = 0.f;
    for (int b = 0; b < BB; ++b) { float var = stats[(b * CH + c) * 2 + 1]; acc += var / (var + 1e-5f); }
    float vc = acc / (float)BB;
    float sc = rsqrtf(vc + 1e-5f);
    for (int b = 0; b < BB; ++b) {
        float m = stats[(b * CH + c) * 2];
        float var = stats[(b * CH + c) * 2 + 1];
        float a = rsqrtf(var + 1e-5f) * sc;
        ab[(b * CH + c) * 2] = a;
        ab[(b * CH + c) * 2 + 1] = -m * a;
    }
}

__global__ void k_resadd(const float* __restrict__ Bm, const float* __restrict__ ab,
                         const float* __restrict__ x, float* __restrict__ y) {
    int i = blockIdx.x * 256 + threadIdx.x;
    if (i >= BB * CH * NN) return;
    int bc = i / NN;
    float v = ab[bc * 2] * Bm[i] + ab[bc * 2 + 1] + x[i];
    y[i] = fmaxf(v, 0.f);
}

// ---------------------------------------------------------------------------
// logit + weighted XwX
// ---------------------------------------------------------------------------
__global__ void k_logit(const float* __restrict__ x4, const float* __restrict__ wl,
                        const float* __restrict__ bl, float* __restrict__ outLogit) {
    int b = blockIdx.x >> 3, chunk = blockIdx.x & 7;
    int n = chunk * 256 + threadIdx.x;
    if (n >= NN) return;
    float acc = 0.f;
    for (int c = 0; c < CH; ++c) acc += wl[c] * x4[(b * CH + c) * NN + n];
    outLogit[b * NN + n] = acc + bl[0];
}

__global__ __launch_bounds__(256) void k_xwx(const float* __restrict__ logit, const float* __restrict__ x_in,
                                             float* __restrict__ XwX) {
    int b = blockIdx.x;
    int tid = threadIdx.x;
    float a[45];
#pragma unroll
    for (int q = 0; q < 45; ++q) a[q] = 0.f;
    for (int n = tid; n < NN; n += 256) {
        float lg = logit[b * NN + n];
        float w = fmaxf(tanhf(lg), 0.f);
        const float* xp = x_in + (b * NN + n) * 4;
        float px = xp[0], py = xp[1], z = xp[2], wq = xp[3];
        float X9[9] = {z * px, z * py, z, wq * px, wq * py, wq, px, py, 1.f};
        int t = 0;
#pragma unroll
        for (int p = 0; p < 9; ++p) {
            float wp = w * X9[p];
#pragma unroll
            for (int q = p; q < 9; ++q) { a[t] += wp * X9[q]; ++t; }
        }
    }
#pragma unroll 1
    for (int q = 0; q < 45; ++q) {
        float v = a[q];
        for (int off = 32; off > 0; off >>= 1) v += __shfl_down(v, off, 64);
        a[q] = v;
    }
    __shared__ float sh[4][45];
    int lane = tid & 63, wid = tid >> 6;
    if (lane == 0) {
        for (int q = 0; q < 45; ++q) sh[wid][q] = a[q];
    }
    __syncthreads();
    if (tid < 45) XwX[b * 45 + tid] = sh[0][tid] + sh[1][tid] + sh[2][tid] + sh[3][tid];
}

// ---------------------------------------------------------------------------
// 9x9 symmetric eigensolver — faithful LAPACK ssyevd (f32) emulation:
// ssytd2 (lower) + ssteqr + sormtr back-transform, f32 LAPACK constants,
// LAPACK >=3.10 slartg (c >= 0).  Verified passing in r3/r4 — arithmetic
// untouched since.
// r5 restructure: ONE MATRIX PER BLOCK (grid 16, lane 0 active).  r4 ran all
// 16 matrices as 16 divergent lanes of one wave — data-dependent ssteqr
// control flow serialized the union of 16 serial programs on one SIMD
// (269 us, 0.012% occupancy).  Same code, same op order per matrix; only the
// mapping changed.
// ---------------------------------------------------------------------------
__device__ inline float slapy2_f(float x, float y) {
    float xa = fabsf(x), ya = fabsf(y);
    float w = fmaxf(xa, ya), z = fminf(xa, ya);
    if (z == 0.f) return w;
    float q = z / w;
    return w * sqrtf(1.f + q * q);
}

__device__ inline void slartg_f(float f, float g, float& c, float& s, float& r) {
    if (g == 0.f) { c = 1.f; s = 0.f; r = f; }
    else if (f == 0.f) { c = 0.f; s = (g > 0.f ? 1.f : -1.f); r = fabsf(g); }
    else {
        float d = sqrtf(f * f + g * g);
        c = fabsf(f) / d;
        r = (f >= 0.f) ? d : -d;
        s = g / r;
    }
}

__device__ void slaev2_f(float a, float b, float c, float& rt1, float& rt2, float& cs1, float& sn1) {
    float sm = a + c, df = a - c;
    float adf = fabsf(df), tb = b + b, ab = fabsf(tb);
    float acmx, acmn;
    if (fabsf(a) > fabsf(c)) { acmx = a; acmn = c; } else { acmx = c; acmn = a; }
    float rt;
    if (adf > ab) { float q = ab / adf; rt = adf * sqrtf(1.f + q * q); }
    else if (adf < ab) { float q = adf / ab; rt = ab * sqrtf(1.f + q * q); }
    else rt = ab * sqrtf(2.f);
    int sgn1;
    if (sm < 0.f) { rt1 = 0.5f * (sm - rt); sgn1 = -1; rt2 = (acmx / rt1) * acmn - (b / rt1) * b; }
    else if (sm > 0.f) { rt1 = 0.5f * (sm + rt); sgn1 = 1; rt2 = (acmx / rt1) * acmn - (b / rt1) * b; }
    else { rt1 = 0.5f * rt; rt2 = -0.5f * rt; sgn1 = 1; }
    float cs; int sgn2;
    if (df >= 0.f) { cs = df + rt; sgn2 = 1; } else { cs = df - rt; sgn2 = -1; }
    float acs = fabsf(cs);
    if (acs > ab) {
        float ct = -tb / cs;
        sn1 = 1.f / sqrtf(1.f + ct * ct);
        cs1 = ct * sn1;
    } else {
        if (ab == 0.f) { cs1 = 1.f; sn1 = 0.f; }
        else { float tn = -cs / tb; cs1 = 1.f / sqrtf(1.f + tn * tn); sn1 = tn * cs1; }
    }
    if (sgn1 == sgn2) { float tn = cs1; cs1 = -sn1; sn1 = tn; }
}

__global__ __launch_bounds__(64) void k_eigh(const float* __restrict__ XwX, float* __restrict__ out_e) {
    __shared__ float Am[81];
    __shared__ float Zm[81];
    int bb = blockIdx.x;
    if (threadIdx.x != 0) return;
#define AA(i, j) Am[(i) * 9 + (j)]
#define ZZ(i, j) Zm[(i) * 9 + (j)]
    {
        const float* src = XwX + bb * 45;
        int t = 0;
        for (int p = 0; p < 9; ++p)
            for (int q = p; q < 9; ++q) { float v = src[t++]; AA(p, q) = v; AA(q, p) = v; }
    }
    float d[9], e[9], tau[9];
    for (int i = 0; i < 8; ++i) {
        float alpha = AA(i + 1, i);
        float xn2 = 0.f;
        for (int j = i + 2; j < 9; ++j) xn2 += AA(j, i) * AA(j, i);
        float taui;
        if (xn2 == 0.f) { taui = 0.f; e[i] = alpha; }
        else {
            float xnorm = sqrtf(xn2);
            float beta = slapy2_f(alpha, xnorm);
            beta = (alpha >= 0.f) ? -beta : beta;
            taui = (beta - alpha) / beta;
            float scl = 1.f / (alpha - beta);
            for (int j = i + 2; j < 9; ++j) AA(j, i) *= scl;
            e[i] = beta;
            float p[9], w[9];
            for (int j = i + 1; j < 9; ++j) {
                float acc = AA(j, i + 1);
                for (int k2 = i + 2; k2 < 9; ++k2) acc += AA(j, k2) * AA(k2, i);
                p[j] = taui * acc;
            }
            float dot = p[i + 1];
            for (int j = i + 2; j < 9; ++j) dot += p[j] * AA(j, i);
            float alpha2 = -0.5f * taui * dot;
            w[i + 1] = p[i + 1] + alpha2;
            for (int j = i + 2; j < 9; ++j) w[j] = p[j] + alpha2 * AA(j, i);
            for (int j = i + 1; j < 9; ++j) {
                float vj = (j == i + 1) ? 1.f : AA(j, i);
                for (int k2 = i + 1; k2 < 9; ++k2) {
                    float vk = (k2 == i + 1) ? 1.f : AA(k2, i);
                    AA(j, k2) -= vj * w[k2] + w[j] * vk;
                }
            }
        }
        tau[i] = taui;
    }
    for (int i = 0; i < 9; ++i) d[i] = AA(i, i);
    for (int i = 0; i < 81; ++i) Zm[i] = 0.f;
    for (int i = 0; i < 9; ++i) ZZ(i, i) = 1.f;
    const float eps = 5.9604645e-08f;
    const float eps2 = 3.5527137e-15f;
    const float safmin = 1.17549435e-38f;
    const int n = 9;
    int nmaxit = n * 30, jtot = 0;
    int l1 = 0;
    while (l1 <= n - 1) {
        if (l1 > 0) e[l1 - 1] = 0.f;
        int m = n - 1;
        for (int mm = l1; mm <= n - 2; ++mm) {
            float tst = fabsf(e[mm]);
            if (tst == 0.f) { m = mm; break; }
            if (tst <= (sqrtf(fabsf(d[mm])) * sqrtf(fabsf(d[mm + 1]))) * eps) { e[mm] = 0.f; m = mm; break; }
        }
        int l = l1, lsv = l, lend = m, lendsv = lend;
        l1 = m + 1;
        if (lend == l) continue;
        if (fabsf(d[lend]) < fabsf(d[l])) { lend = lsv; l = lendsv; }
        if (lend > l) {
            for (;;) {
                int m2 = lend;
                if (l != lend) {
                    for (int mm = l; mm <= lend - 1; ++mm) {
                        float tst = e[mm] * e[mm];
                        if (tst <= (eps2 * fabsf(d[mm])) * fabsf(d[mm + 1]) + safmin) { m2 = mm; break; }
                    }
                }
                if (m2 < lend) e[m2] = 0.f;
                float p = d[l];
                if (m2 == l) { d[l] = p; ++l; if (l <= lend) continue; else break; }
                if (m2 == l + 1) {
                    float rt1, rt2, c, s;
                    slaev2_f(d[l], e[l], d[l + 1], rt1, rt2, c, s);
                    for (int r2 = 0; r2 < 9; ++r2) {
                        float tmp = ZZ(r2, l + 1);
                        ZZ(r2, l + 1) = c * tmp - s * ZZ(r2, l);
                        ZZ(r2, l) = s * tmp + c * ZZ(r2, l);
                    }
                    d[l] = rt1; d[l + 1] = rt2; e[l] = 0.f; l += 2;
                    if (l <= lend) continue; else break;
                }
                if (jtot == nmaxit) break;
                ++jtot;
                float g = (d[l + 1] - p) / (2.f * e[l]);
                float r = slapy2_f(g, 1.f);
                g = d[m2] - p + e[l] / (g + (g >= 0.f ? fabsf(r) : -fabsf(r)));
                float s = 1.f, c = 1.f;
                p = 0.f;
                float csv[9], snv[9];
                for (int i = m2 - 1; i >= l; --i) {
                    float f = s * e[i], bq = c * e[i];
                    slartg_f(g, f, c, s, r);
                    if (i != m2 - 1) e[i + 1] = r;
                    g = d[i + 1] - p;
                    r = (d[i] - g) * s + 2.f * c * bq;
                    p = s * r;
                    d[i + 1] = g + p;
                    g = c * r - bq;
                    csv[i] = c; snv[i] = -s;
                }
                for (int jj = m2 - 1; jj >= l; --jj) {
                    float cj = csv[jj], sj = snv[jj];
                    for (int r2 = 0; r2 < 9; ++r2) {
                        float tmp = ZZ(r2, jj + 1);
                        ZZ(r2, jj + 1) = cj * tmp - sj * ZZ(r2, jj);
                        ZZ(r2, jj) = sj * tmp + cj * ZZ(r2, jj);
                    }
                }
                d[l] -= p; e[l] = g;
            }
        } else {
            for (;;) {
                int m2 = lend;
                if (l != lend) {
                    for (int mm = l; mm >= lend + 1; --mm) {
                        float tst = e[mm - 1] * e[mm - 1];
                        if (tst <= (eps2 * fabsf(d[mm])) * fabsf(d[mm - 1]) + safmin) { m2 = mm; break; }
                    }
                }
                if (m2 > lend) e[m2 - 1] = 0.f;
                float p = d[l];
                if (m2 == l) { d[l] = p; --l; if (l >= lend) continue; else break; }
                if (m2 == l - 1) {
                    float rt1, rt2, c, s;
                    slaev2_f(d[l - 1], e[l - 1], d[l], rt1, rt2, c, s);
                    for (int r2 = 0; r2 < 9; ++r2) {
                        float tmp = ZZ(r2, l);
                        ZZ(r2, l) = c * tmp - s * ZZ(r2, l - 1);
                        ZZ(r2, l - 1) = s * tmp + c * ZZ(r2, l - 1);
                    }
                    d[l - 1] = rt1; d[l] = rt2; e[l - 1] = 0.f; l -= 2;
                    if (l >= lend) continue; else break;
                }
                if (jtot == nmaxit) break;
                ++jtot;
                float g = (d[l - 1] - p) / (2.f * e[l - 1]);
                float r = slapy2_f(g, 1.f);
                g = d[m2] - p + e[l - 1] / (g + (g >= 0.f ? fabsf(r) : -fabsf(r)));
                float s = 1.f, c = 1.f;
                p = 0.f;
                float csv[9], snv[9];
                for (int i = m2; i <= l - 1; ++i) {
                    float f = s * e[i], bq = c * e[i];
                    slartg_f(g, f, c, s, r);
                    if (i != m2) e[i - 1] = r;
                    g = d[i] - p;
                    r = (d[i + 1] - g) * s + 2.f * c * bq;
                    p = s * r;
                    d[i] = g + p;
                    g = c * r - bq;
                    csv[i] = c; snv[i] = s;
                }
                for (int jj = m2; jj <= l - 1; ++jj) {
                    float cj = csv[jj], sj = snv[jj];
                    for (int r2 = 0; r2 < 9; ++r2) {
                        float tmp = ZZ(r2, jj + 1);
                        ZZ(r2, jj + 1) = cj * tmp - sj * ZZ(r2, jj);
                        ZZ(r2, jj) = sj * tmp + cj * ZZ(r2, jj);
                    }
                }
                d[l] -= p; e[l - 1] = g;
            }
        }
    }
    for (int ii = 1; ii < 9; ++ii) {
        int i = ii - 1, kk = i;
        float p = d[i];
        for (int j = ii; j < 9; ++j)
            if (d[j] < p) { kk = j; p = d[j]; }
        if (kk != i) {
            d[kk] = d[i]; d[i] = p;
            for (int r2 = 0; r2 < 9; ++r2) { float tmp = ZZ(r2, i); ZZ(r2, i) = ZZ(r2, kk); ZZ(r2, kk) = tmp; }
        }
    }
    float v0[9];
    for (int r2 = 0; r2 < 9; ++r2) v0[r2] = ZZ(r2, 0);
    for (int i = 7; i >= 0; --i) {
        float ti = tau[i];
        if (ti == 0.f) continue;
        float dot = v0[i + 1];
        for (int j = i + 2; j < 9; ++j) dot += AA(j, i) * v0[j];
        dot *= ti;
        v0[i + 1] -= dot;
        for (int j = i + 2; j < 9; ++j) v0[j] -= AA(j, i) * dot;
    }
    float nrm = 0.f;
    for (int r2 = 0; r2 < 9; ++r2) nrm += v0[r2] * v0[r2];
    nrm = sqrtf(nrm);
    for (int r2 = 0; r2 < 9; ++r2) out_e[bb * 9 + r2] = v0[r2] / nrm;
#undef AA
#undef ZZ
}

// ---------------------------------------------------------------------------
// launch
// ---------------------------------------------------------------------------
extern "C" void kernel_launch(void* const* d_in, const int* in_sizes, int n_in,
                              void* d_out, int out_size, void* d_ws, size_t ws_size,
                              hipStream_t stream) {
    const float* data = (const float*)d_in[0];
    const float* x_in = (const float*)d_in[1];
    const float* w1a = (const float*)d_in[2];
    const float* b1a = (const float*)d_in[3];
    const float* w1b = (const float*)d_in[4];
    const float* b1b = (const float*)d_in[5];
    const float* w2 = (const float*)d_in[6];
    const float* b2 = (const float*)d_in[7];
    const float* res_wa = (const float*)d_in[8];
    const float* res_ba = (const float*)d_in[9];
    const float* res_wb = (const float*)d_in[10];
    const float* res_bb = (const float*)d_in[11];
    const float* wl = (const float*)d_in[12];
    const float* bl = (const float*)d_in[13];
    float* out = (float*)d_out;

    // workspace layout
    double* gacc = (double*)d_ws;                       // 65 doubles (needs memset)
    float* xwx = (float*)((char*)d_ws + 1024);          // 16*45 floats
    float* fbase = (float*)((char*)d_ws + 8192);
    float* big0 = fbase;
    float* big1 = big0 + BB * CH * NN;
    float* big2 = big1 + BB * CH * NN;
    float* tbuf = big2 + BB * CH * NN;
    float* f5 = tbuf + BB * 4 * NN;
    float* invn = f5 + BB * 5 * NN;
    float* Sv = invn + BB * NN;
    int* idxb = (int*)(Sv + BB * CH);
    float* chAB = (float*)(idxb + BB * NN * 8);
    float* stA = chAB + 256;
    float* abA = stA + BB * CH * 2;
    float* stB = abA + BB * CH * 2;
    float* abB = stB + BB * CH * 2;
    float* g2ab = abB + BB * CH * 2;
    // kNN partials live in big2 (free until the res-blocks)
    float* knn_pd = big2;
    int* knn_pj = (int*)(big2 + BB * NN * JCH * 8);

    hipMemsetAsync(d_ws, 0, 1024, stream);

    k_build_t<<<500, 256, 0, stream>>>(data, tbuf);
    k_conv1<<<16000, 256, 0, stream>>>(tbuf, w1a, b1a, big0);
    k_chanstats<<<128, 256, 0, stream>>>(big0, chAB);
    k_gemm<<<dim3(2, 512), 256, 0, stream>>>(big0, w1b, b1b, big1, chAB, 1);  // h2 in big1
    k_invn<<<128, 256, 0, stream>>>(big1, invn);
    k_S<<<2048, 256, 0, stream>>>(big1, invn, Sv);
    k_Df<<<128, 256, 0, stream>>>(big1, invn, Sv, tbuf, out, f5);
    k_knn_part<<<dim3(JCH, 8, BB), 256, 0, stream>>>(f5, knn_pd, knn_pj);
    k_knn_merge<<<125, 256, 0, stream>>>(knn_pd, knn_pj, idxb);
    k_gstats<<<125, 256, 0, stream>>>(f5, idxb, gacc);
    k_gfinal<<<1, 128, 0, stream>>>(gacc, w2, b2, g2ab);
    k_graphconv<<<2000, 256, 0, stream>>>(f5, idxb, w2, b2, g2ab, big0);  // x0 in big0

    float* xb = big0;
    float* hb = big1;
    for (int i = 0; i < 4; ++i) {
        k_gemm<<<dim3(2, 512), 256, 0, stream>>>(xb, res_wa + i * CH * CH, res_ba + i * CH, hb, nullptr, 0);
        k_rowstats<<<2048, 256, 0, stream>>>(hb, stA);
        k_finalize<<<1, 128, 0, stream>>>(stA, abA);
        k_gemm<<<dim3(2, 512), 256, 0, stream>>>(hb, res_wb + i * CH * CH, res_bb + i * CH, big2, abA, 2);
        k_rowstats<<<2048, 256, 0, stream>>>(big2, stB);
        k_finalize<<<1, 128, 0, stream>>>(stB, abB);
        k_resadd<<<16000, 256, 0, stream>>>(big2, abB, xb, hb);
        float* tmp = xb; xb = hb; hb = tmp;
    }

    k_logit<<<128, 256, 0, stream>>>(xb, wl, bl, out + BB * NN);
    k_xwx<<<16, 256, 0, stream>>>(out + BB * NN, x_in, xwx);
    k_eigh<<<16, 64, 0, stream>>>(xwx, out + 2 * BB * NN);
}

// Round 6
// 866.293 us; speedup vs baseline: 1.4258x; 1.0881x over previous
//
#include <hip/hip_runtime.h>
#include <math.h>

#define BB 16
#define NN 2000
#define CH 128
#define KNN 8
#define JCH 8
#define JSZ 250  // NN / JCH

// ---------------------------------------------------------------------------
// helpers
// ---------------------------------------------------------------------------
__device__ inline float wred(float v) {
    for (int off = 32; off > 0; off >>= 1) v += __shfl_down(v, off, 64);
    return v;
}

// ---------------------------------------------------------------------------
// stage 0: t[b,c,n] = data[b,0,n,c]
// ---------------------------------------------------------------------------
__global__ void k_build_t(const float* __restrict__ data, float* __restrict__ t) {
    int i = blockIdx.x * 256 + threadIdx.x;
    if (i >= BB * 4 * NN) return;
    int n = i % NN;
    int c = (i / NN) & 3;
    int b = i / (4 * NN);
    t[i] = data[(b * NN + n) * 4 + c];
}

// conv1: c1[b,o,n] = sum_c w1a[o,c]*t[b,c,n] + b1a[o]
__global__ void k_conv1(const float* __restrict__ t, const float* __restrict__ w1a,
                        const float* __restrict__ b1a, float* __restrict__ c1) {
    int i = blockIdx.x * 256 + threadIdx.x;  // (b*128+o)*N+n
    if (i >= BB * CH * NN) return;
    int n = i % NN;
    int rest = i / NN;
    int o = rest & 127;
    int b = rest >> 7;
    float acc = b1a[o];
    for (int c = 0; c < 4; ++c) acc += w1a[o * 4 + c] * t[(b * 4 + c) * NN + n];
    c1[i] = acc;
}

// per-channel bn stats over (b,n): 128 blocks
__global__ void k_chanstats(const float* __restrict__ src, float* __restrict__ chAB) {
    int o = blockIdx.x;
    int tid = threadIdx.x;
    float s = 0.f, ss = 0.f;
    for (int b = 0; b < BB; ++b) {
        const float* p = src + (b * CH + o) * NN;
        for (int n = tid; n < NN; n += 256) { float v = p[n]; s += v; ss += v * v; }
    }
    s = wred(s); ss = wred(ss);
    __shared__ float sh[8];
    int wid = tid >> 6, lane = tid & 63;
    if (lane == 0) { sh[wid] = s; sh[4 + wid] = ss; }
    __syncthreads();
    if (tid == 0) {
        float S0 = sh[0] + sh[1] + sh[2] + sh[3];
        float SS = sh[4] + sh[5] + sh[6] + sh[7];
        float m = S0 / (float)(BB * NN);
        float var = SS / (float)(BB * NN) - m * m;
        float a = rsqrtf(var + 1e-5f);
        chAB[o] = a;
        chAB[CH + o] = -m * a;
    }
}

// ---------------------------------------------------------------------------
// generic 128x128 GEMM over columns (b,n), with input transform.
// mode 0: raw; mode 1: relu(chAB[j]*x + chAB[128+j]); mode 2: relu(ab[(b*128+j)*2]*x + ab[..+1])
// grid: (2, B*32), block 256.  tile: 64 o x 64 n.
// FMA accumulation order is IDENTICAL to the r3 baseline — do not reorder
// (absmax margin 0.34/0.4225 depends on it).
// ---------------------------------------------------------------------------
__global__ __launch_bounds__(256) void k_gemm(const float* __restrict__ X, const float* __restrict__ W,
                                              const float* __restrict__ bias, float* __restrict__ Y,
                                              const float* __restrict__ ab, int mode) {
    int ot = blockIdx.x, by = blockIdx.y;
    int b = by >> 5, nt = by & 31;
    int n0 = nt * 64, o0 = ot * 64;
    int tid = threadIdx.x;
    int tx = tid & 15, ty = tid >> 4;
    __shared__ float Xs[32][64];
    __shared__ float Ws[32][68];
    float acc[4][4] = {};
    for (int jc = 0; jc < 4; ++jc) {
        for (int q = 0; q < 8; ++q) {
            int e = q * 256 + tid;
            int jj = e >> 6, nn = e & 63;
            int j = jc * 32 + jj, n = n0 + nn;
            float v = 0.f;
            if (n < NN) {
                v = X[(b * CH + j) * NN + n];
                if (mode == 1) v = fmaxf(ab[j] * v + ab[CH + j], 0.f);
                else if (mode == 2) { int bc = b * CH + j; v = fmaxf(ab[bc * 2] * v + ab[bc * 2 + 1], 0.f); }
            }
            Xs[jj][nn] = v;
        }
        for (int q = 0; q < 8; ++q) {
            int e = q * 256 + tid;
            int jj = e & 31, oo = e >> 5;
            Ws[jj][oo] = W[(o0 + oo) * CH + jc * 32 + jj];
        }
        __syncthreads();
        for (int jj = 0; jj < 32; ++jj) {
            float4 wv = *(const float4*)&Ws[jj][ty * 4];
            float4 xv = *(const float4*)&Xs[jj][tx * 4];
            float wva[4] = {wv.x, wv.y, wv.z, wv.w};
            float xva[4] = {xv.x, xv.y, xv.z, xv.w};
#pragma unroll
            for (int a = 0; a < 4; ++a)
#pragma unroll
                for (int bq = 0; bq < 4; ++bq) acc[a][bq] += wva[a] * xva[bq];
        }
        __syncthreads();
    }
    for (int a = 0; a < 4; ++a) {
        int o = o0 + ty * 4 + a;
        float bi = bias[o];
        for (int q = 0; q < 4; ++q) {
            int n = n0 + tx * 4 + q;
            if (n < NN) Y[(b * CH + o) * NN + n] = acc[a][q] + bi;
        }
    }
}

// ---------------------------------------------------------------------------
// stage 1 tail: channel-norm, S, D, f5
// ---------------------------------------------------------------------------
__global__ void k_invn(const float* __restrict__ h2, float* __restrict__ invn) {
    int b = blockIdx.x >> 3, chunk = blockIdx.x & 7;
    int n = chunk * 256 + threadIdx.x;
    if (n >= NN) return;
    float acc = 0.f;
    for (int c = 0; c < CH; ++c) { float v = h2[(b * CH + c) * NN + n]; acc += v * v; }
    invn[b * NN + n] = 1.f / (sqrtf(acc) + 1e-5f);
}

__global__ void k_S(const float* __restrict__ h2, const float* __restrict__ invn, float* __restrict__ Sv) {
    int row = blockIdx.x;  // b*128+c
    int b = row >> 7;
    const float* p = h2 + row * NN;
    const float* iv = invn + b * NN;
    float s = 0.f;
    for (int n = threadIdx.x; n < NN; n += 256) s += p[n] * iv[n];
    s = wred(s);
    __shared__ float sh[4];
    int wid = threadIdx.x >> 6, lane = threadIdx.x & 63;
    if (lane == 0) sh[wid] = s;
    __syncthreads();
    if (threadIdx.x == 0) Sv[row] = sh[0] + sh[1] + sh[2] + sh[3];
}

__global__ void k_Df(const float* __restrict__ h2, const float* __restrict__ invn,
                     const float* __restrict__ Sv, const float* __restrict__ t,
                     float* __restrict__ outD, float* __restrict__ f5) {
    int b = blockIdx.x >> 3, chunk = blockIdx.x & 7;
    int n = chunk * 256 + threadIdx.x;
    if (n >= NN) return;
    float acc = 0.f;
    for (int c = 0; c < CH; ++c) acc += h2[(b * CH + c) * NN + n] * Sv[b * CH + c];
    float Ar = acc * invn[b * NN + n];
    float Dv = (Ar - 1.0f) / (float)NN;
    outD[b * NN + n] = Dv;
    for (int c = 0; c < 4; ++c) f5[(b * 5 + c) * NN + n] = t[(b * 4 + c) * NN + n];
    f5[(b * 5 + 4) * NN + n] = fmaxf(tanhf(Dv), 0.f);
}

// ---------------------------------------------------------------------------
// kNN stage A: per (b, i, j-chunk) partial top-8 over 250 candidates.
// r6: register-resident top-8.  r5's runtime-indexed insertion put bd[]/bj[]
// in scratch (VGPR_Count=28 proved it) — 196 us, VALUBusy 105%.  The swap
// chain below uses only compile-time indices after unroll -> pure
// v_cmp/v_cndmask in VGPRs.  Selection semantics identical (strict <, equal
// d lands after existing -> lower-j-first stable).  LDS staged as float4+f
// so each candidate is ds_read_b128 + ds_read_b32 (was 5x ds_read_b32).
// Distance expression unchanged (same FP order as r3).
// ---------------------------------------------------------------------------
__global__ __launch_bounds__(256) void k_knn_part(const float* __restrict__ f5,
                                                  float* __restrict__ pd, int* __restrict__ pj) {
    __shared__ float4 fs4[JSZ];
    __shared__ float fs1[JSZ];
    int jc = blockIdx.x, ic = blockIdx.y, b = blockIdx.z;
    int j0 = jc * JSZ;
    int tid = threadIdx.x;
    const float* fb = f5 + b * 5 * NN;
    for (int e = tid; e < JSZ; e += 256) {
        float4 v;
        v.x = fb[0 * NN + j0 + e];
        v.y = fb[1 * NN + j0 + e];
        v.z = fb[2 * NN + j0 + e];
        v.w = fb[3 * NN + j0 + e];
        fs4[e] = v;
        fs1[e] = fb[4 * NN + j0 + e];
    }
    __syncthreads();
    int i = ic * 256 + tid;
    if (i >= NN) return;
    float fi0 = fb[i], fi1 = fb[NN + i], fi2 = fb[2 * NN + i], fi3 = fb[3 * NN + i], fi4 = fb[4 * NN + i];
    float bd[8]; int bj[8];
#pragma unroll
    for (int q = 0; q < 8; ++q) { bd[q] = 1e30f; bj[q] = 0x7fffffff; }
    for (int jj = 0; jj < JSZ; ++jj) {
        float4 fj = fs4[jj];
        float fj4 = fs1[jj];
        int j = j0 + jj;
        float d0 = fi0 - fj.x, d1 = fi1 - fj.y, d2 = fi2 - fj.z;
        float d3 = fi3 - fj.w, d4 = fi4 - fj4;
        float d = d0 * d0 + d1 * d1 + d2 * d2 + d3 * d3 + d4 * d4;
        if (j != i && d < bd[7]) {
            float cd = d; int cj = j;
#pragma unroll
            for (int q = 0; q < 8; ++q) {
                bool lt = cd < bd[q];
                float td = lt ? bd[q] : cd;
                int tj = lt ? bj[q] : cj;
                bd[q] = lt ? cd : bd[q];
                bj[q] = lt ? cj : bj[q];
                cd = td; cj = tj;
            }
        }
    }
    long base = ((long)(b * NN + i) * JCH + jc) * 8;
#pragma unroll
    for (int q = 0; q < 8; ++q) { pd[base + q] = bd[q]; pj[base + q] = bj[q]; }
}

// kNN stage B: 8-way merge of sorted partial lists.
__global__ __launch_bounds__(256) void k_knn_merge(const float* __restrict__ pd, const int* __restrict__ pj,
                                                   int* __restrict__ idxb) {
    int s = blockIdx.x * 256 + threadIdx.x;  // b*NN + i
    if (s >= BB * NN) return;
    const float* dl = pd + (long)s * JCH * 8;
    const int* jl = pj + (long)s * JCH * 8;
    int ptr[JCH];
#pragma unroll
    for (int c = 0; c < JCH; ++c) ptr[c] = 0;
    for (int q = 0; q < 8; ++q) {
        float best = 1e38f; int bestj = 0x7fffffff; int bc = 0;
#pragma unroll
        for (int c = 0; c < JCH; ++c) {
            if (ptr[c] < 8) {
                float d = dl[c * 8 + ptr[c]];
                int j = jl[c * 8 + ptr[c]];
                if (d < best || (d == best && j < bestj)) { best = d; bestj = j; bc = c; }
            }
        }
        idxb[s * 8 + q] = bestj;
        ++ptr[bc];
    }
}

// ---------------------------------------------------------------------------
// graph-feature statistics: 10 means + 55 second moments (f64 accumulators)
// ---------------------------------------------------------------------------
__global__ __launch_bounds__(256) void k_gstats(const float* __restrict__ f5, const int* __restrict__ idxb,
                                                double* __restrict__ gacc) {
    int s = blockIdx.x * 256 + threadIdx.x;
    float acc[65];
#pragma unroll
    for (int q = 0; q < 65; ++q) acc[q] = 0.f;
    if (s < BB * NN) {
        int b = s / NN, n = s - b * NN;
        float fo[5];
#pragma unroll
        for (int c = 0; c < 5; ++c) fo[c] = f5[(b * 5 + c) * NN + n];
        float sd[5] = {0, 0, 0, 0, 0};
        float sdd[15];
#pragma unroll
        for (int q = 0; q < 15; ++q) sdd[q] = 0.f;
        for (int k = 0; k < 8; ++k) {
            int j = idxb[s * 8 + k];
            float df[5];
#pragma unroll
            for (int c = 0; c < 5; ++c) df[c] = fo[c] - f5[(b * 5 + c) * NN + j];
#pragma unroll
            for (int c = 0; c < 5; ++c) sd[c] += df[c];
            int t = 0;
#pragma unroll
            for (int c = 0; c < 5; ++c)
#pragma unroll
                for (int d2 = c; d2 < 5; ++d2) { sdd[t] += df[c] * df[d2]; ++t; }
        }
#pragma unroll
        for (int c = 0; c < 5; ++c) { acc[c] = 8.f * fo[c]; acc[5 + c] = sd[c]; }
        int t = 10, sc = 0;
        for (int p = 0; p < 10; ++p)
            for (int q = p; q < 10; ++q) {
                float v;
                if (q < 5) v = 8.f * fo[p] * fo[q];
                else if (p < 5) v = fo[p] * sd[q - 5];
                else { v = sdd[sc]; ++sc; }
                acc[t++] = v;
            }
    }
#pragma unroll 1
    for (int q = 0; q < 65; ++q) {
        float v = acc[q];
        for (int off = 32; off > 0; off >>= 1) v += __shfl_down(v, off, 64);
        acc[q] = v;
    }
    __shared__ float sh[4][65];
    int lane = threadIdx.x & 63, wid = threadIdx.x >> 6;
    if (lane == 0) {
        for (int q = 0; q < 65; ++q) sh[wid][q] = acc[q];
    }
    __syncthreads();
    if (threadIdx.x < 65) {
        float tot = sh[0][threadIdx.x] + sh[1][threadIdx.x] + sh[2][threadIdx.x] + sh[3][threadIdx.x];
        atomicAdd(&gacc[threadIdx.x], (double)tot);
    }
}

__global__ void k_gfinal(const double* __restrict__ gacc, const float* __restrict__ w2,
                         const float* __restrict__ b2, float* __restrict__ g2ab) {
    int o = threadIdx.x;
    if (o >= 128) return;
    double inv = 1.0 / (double)(BB * NN * 8);
    double Wr[10];
    for (int c = 0; c < 10; ++c) Wr[c] = (double)w2[o * 10 + c];
    double gm[10];
    for (int c = 0; c < 10; ++c) gm[c] = gacc[c] * inv;
    double b0 = (double)b2[o];
    double mean = b0;
    for (int c = 0; c < 10; ++c) mean += Wr[c] * gm[c];
    double e2 = b0 * b0 + 2.0 * b0 * (mean - b0);
    int t = 10;
    for (int p = 0; p < 10; ++p)
        for (int q = p; q < 10; ++q) {
            double G = gacc[t] * inv; ++t;
            double contrib = Wr[p] * Wr[q] * G;
            e2 += (p == q) ? contrib : 2.0 * contrib;
        }
    double var = e2 - mean * mean;
    double a = 1.0 / sqrt(var + 1e-5);
    g2ab[o] = (float)a;
    g2ab[128 + o] = (float)(-mean * a);
}

// graph conv + max over k + bn + relu (bn commutes with max since scale>0)
__global__ __launch_bounds__(256) void k_graphconv(const float* __restrict__ f5, const int* __restrict__ idxb,
                                                   const float* __restrict__ w2, const float* __restrict__ b2,
                                                   const float* __restrict__ g2ab, float* __restrict__ x0) {
    __shared__ float ws[1280], bs[128];
    __shared__ float fo_s[16][5], fnb_s[16][8][5];
    __shared__ int idxs[16][8];
    int b = blockIdx.x / 125, tile = blockIdx.x % 125;
    int nbase = tile * 16;
    int tid = threadIdx.x;
    for (int e = tid; e < 1280; e += 256) ws[e] = w2[e];
    if (tid < 128) bs[tid] = b2[tid];
    if (tid < 128) { int nn = tid >> 3, k = tid & 7; idxs[nn][k] = idxb[(b * NN + nbase + nn) * 8 + k]; }
    if (tid >= 128 && tid < 208) { int e = tid - 128; int nn = e / 5, c = e % 5; fo_s[nn][c] = f5[(b * 5 + c) * NN + nbase + nn]; }
    __syncthreads();
    for (int e = tid; e < 640; e += 256) {
        int nn = e / 40, r = e % 40, k = r / 5, c = r % 5;
        fnb_s[nn][k][c] = f5[(b * 5 + c) * NN + idxs[nn][k]];
    }
    __syncthreads();
    int nn = tid & 15, og = tid >> 4;
    float fo[5];
#pragma unroll
    for (int c = 0; c < 5; ++c) fo[c] = fo_s[nn][c];
    for (int oo = 0; oo < 8; ++oo) {
        int o = og * 8 + oo;
        float base = bs[o];
        float wn[5];
#pragma unroll
        for (int c = 0; c < 5; ++c) {
            float w1 = ws[o * 10 + c], w5 = ws[o * 10 + 5 + c];
            base += (w1 + w5) * fo[c];
            wn[c] = w5;
        }
        float mx = -1e30f;
        for (int k = 0; k < 8; ++k) {
            float v = base;
#pragma unroll
            for (int c = 0; c < 5; ++c) v -= wn[c] * fnb_s[nn][k][c];
            mx = fmaxf(mx, v);
        }
        float y = fmaxf(g2ab[o] * mx + g2ab[128 + o], 0.f);
        x0[(b * CH + o) * NN + nbase + nn] = y;
    }
}

// ---------------------------------------------------------------------------
// res-block support
// ---------------------------------------------------------------------------
__global__ void k_rowstats(const float* __restrict__ src, float* __restrict__ stats) {
    int row = blockIdx.x;  // b*128+c
    const float* p = src + row * NN;
    float s = 0.f, ss = 0.f;
    for (int n = threadIdx.x; n < NN; n += 256) { float v = p[n]; s += v; ss += v * v; }
    s = wred(s); ss = wred(ss);
    __shared__ float sh[8];
    int wid = threadIdx.x >> 6, lane = threadIdx.x & 63;
    if (lane == 0) { sh[wid] = s; sh[4 + wid] = ss; }
    __syncthreads();
    if (threadIdx.x == 0) {
        float S0 = sh[0] + sh[1] + sh[2] + sh[3];
        float SS = sh[4] + sh[5] + sh[6] + sh[7];
        float m = S0 / (float)NN;
        float var = SS / (float)NN - m * m;
        stats[row * 2] = m;
        stats[row * 2 + 1] = var;
    }
}

// instn + bn folded into per-(b,c) affine
__global__ void k_finalize(const float* __restrict__ stats, float* __restrict__ ab) {
    int c = threadIdx.x;
    if (c >= 128) return;
    float acc = 0.f;
    for (int b = 0; b < BB; ++b) { float var = stats[(b * CH + c) * 2 + 1]; acc += var / (var + 1e-5f); }
    float vc = acc / (float)BB;
    float sc = rsqrtf(vc + 1e-5f);
    for (int b = 0; b < BB; ++b) {
        float m = stats[(b * CH + c) * 2];
        float var = stats[(b * CH + c) * 2 + 1];
        float a = rsqrtf(var + 1e-5f) * sc;
        ab[(b * CH + c) * 2] = a;
        ab[(b * CH + c) * 2 + 1] = -m * a;
    }
}

__global__ void k_resadd(const float* __restrict__ Bm, const float* __restrict__ ab,
                         const float* __restrict__ x, float* __restrict__ y) {
    int i = blockIdx.x * 256 + threadIdx.x;
    if (i >= BB * CH * NN) return;
    int bc = i / NN;
    float v = ab[bc * 2] * Bm[i] + ab[bc * 2 + 1] + x[i];
    y[i] = fmaxf(v, 0.f);
}

// ---------------------------------------------------------------------------
// logit + weighted XwX
// ---------------------------------------------------------------------------
__global__ void k_logit(const float* __restrict__ x4, const float* __restrict__ wl,
                        const float* __restrict__ bl, float* __restrict__ outLogit) {
    int b = blockIdx.x >> 3, chunk = blockIdx.x & 7;
    int n = chunk * 256 + threadIdx.x;
    if (n >= NN) return;
    float acc = 0.f;
    for (int c = 0; c < CH; ++c) acc += wl[c] * x4[(b * CH + c) * NN + n];
    outLogit[b * NN + n] = acc + bl[0];
}

__global__ __launch_bounds__(256) void k_xwx(const float* __restrict__ logit, const float* __restrict__ x_in,
                                             float* __restrict__ XwX) {
    int b = blockIdx.x;
    int tid = threadIdx.x;
    float a[45];
#pragma unroll
    for (int q = 0; q < 45; ++q) a[q] = 0.f;
    for (int n = tid; n < NN; n += 256) {
        float lg = logit[b * NN + n];
        float w = fmaxf(tanhf(lg), 0.f);
        const float* xp = x_in + (b * NN + n) * 4;
        float px = xp[0], py = xp[1], z = xp[2], wq = xp[3];
        float X9[9] = {z * px, z * py, z, wq * px, wq * py, wq, px, py, 1.f};
        int t = 0;
#pragma unroll
        for (int p = 0; p < 9; ++p) {
            float wp = w * X9[p];
#pragma unroll
            for (int q = p; q < 9; ++q) { a[t] += wp * X9[q]; ++t; }
        }
    }
#pragma unroll 1
    for (int q = 0; q < 45; ++q) {
        float v = a[q];
        for (int off = 32; off > 0; off >>= 1) v += __shfl_down(v, off, 64);
        a[q] = v;
    }
    __shared__ float sh[4][45];
    int lane = tid & 63, wid = tid >> 6;
    if (lane == 0) {
        for (int q = 0; q < 45; ++q) sh[wid][q] = a[q];
    }
    __syncthreads();
    if (tid < 45) XwX[b * 45 + tid] = sh[0][tid] + sh[1][tid] + sh[2][tid] + sh[3][tid];
}

// ---------------------------------------------------------------------------
// 9x9 symmetric eigensolver — faithful LAPACK ssyevd (f32) emulation:
// ssytd2 (lower) + ssteqr + sormtr back-transform, f32 LAPACK constants,
// LAPACK >=3.10 slartg (c >= 0).  One matrix per block (r5).  Verified
// passing r3-r5 — arithmetic untouched.
// ---------------------------------------------------------------------------
__device__ inline float slapy2_f(float x, float y) {
    float xa = fabsf(x), ya = fabsf(y);
    float w = fmaxf(xa, ya), z = fminf(xa, ya);
    if (z == 0.f) return w;
    float q = z / w;
    return w * sqrtf(1.f + q * q);
}

__device__ inline void slartg_f(float f, float g, float& c, float& s, float& r) {
    if (g == 0.f) { c = 1.f; s = 0.f; r = f; }
    else if (f == 0.f) { c = 0.f; s = (g > 0.f ? 1.f : -1.f); r = fabsf(g); }
    else {
        float d = sqrtf(f * f + g * g);
        c = fabsf(f) / d;
        r = (f >= 0.f) ? d : -d;
        s = g / r;
    }
}

__device__ void slaev2_f(float a, float b, float c, float& rt1, float& rt2, float& cs1, float& sn1) {
    float sm = a + c, df = a - c;
    float adf = fabsf(df), tb = b + b, ab = fabsf(tb);
    float acmx, acmn;
    if (fabsf(a) > fabsf(c)) { acmx = a; acmn = c; } else { acmx = c; acmn = a; }
    float rt;
    if (adf > ab) { float q = ab / adf; rt = adf * sqrtf(1.f + q * q); }
    else if (adf < ab) { float q = adf / ab; rt = ab * sqrtf(1.f + q * q); }
    else rt = ab * sqrtf(2.f);
    int sgn1;
    if (sm < 0.f) { rt1 = 0.5f * (sm - rt); sgn1 = -1; rt2 = (acmx / rt1) * acmn - (b / rt1) * b; }
    else if (sm > 0.f) { rt1 = 0.5f * (sm + rt); sgn1 = 1; rt2 = (acmx / rt1) * acmn - (b / rt1) * b; }
    else { rt1 = 0.5f * rt; rt2 = -0.5f * rt; sgn1 = 1; }
    float cs; int sgn2;
    if (df >= 0.f) { cs = df + rt; sgn2 = 1; } else { cs = df - rt; sgn2 = -1; }
    float acs = fabsf(cs);
    if (acs > ab) {
        float ct = -tb / cs;
        sn1 = 1.f / sqrtf(1.f + ct * ct);
        cs1 = ct * sn1;
    } else {
        if (ab == 0.f) { cs1 = 1.f; sn1 = 0.f; }
        else { float tn = -cs / tb; cs1 = 1.f / sqrtf(1.f + tn * tn); sn1 = tn * cs1; }
    }
    if (sgn1 == sgn2) { float tn = cs1; cs1 = -sn1; sn1 = tn; }
}

__global__ __launch_bounds__(64) void k_eigh(const float* __restrict__ XwX, float* __restrict__ out_e) {
    __shared__ float Am[81];
    __shared__ float Zm[81];
    int bb = blockIdx.x;
    if (threadIdx.x != 0) return;
#define AA(i, j) Am[(i) * 9 + (j)]
#define ZZ(i, j) Zm[(i) * 9 + (j)]
    {
        const float* src = XwX + bb * 45;
        int t = 0;
        for (int p = 0; p < 9; ++p)
            for (int q = p; q < 9; ++q) { float v = src[t++]; AA(p, q) = v; AA(q, p) = v; }
    }
    float d[9], e[9], tau[9];
    for (int i = 0; i < 8; ++i) {
        float alpha = AA(i + 1, i);
        float xn2 = 0.f;
        for (int j = i + 2; j < 9; ++j) xn2 += AA(j, i) * AA(j, i);
        float taui;
        if (xn2 == 0.f) { taui = 0.f; e[i] = alpha; }
        else {
            float xnorm = sqrtf(xn2);
            float beta = slapy2_f(alpha, xnorm);
            beta = (alpha >= 0.f) ? -beta : beta;
            taui = (beta - alpha) / beta;
            float scl = 1.f / (alpha - beta);
            for (int j = i + 2; j < 9; ++j) AA(j, i) *= scl;
            e[i] = beta;
            float p[9], w[9];
            for (int j = i + 1; j < 9; ++j) {
                float acc = AA(j, i + 1);
                for (int k2 = i + 2; k2 < 9; ++k2) acc += AA(j, k2) * AA(k2, i);
                p[j] = taui * acc;
            }
            float dot = p[i + 1];
            for (int j = i + 2; j < 9; ++j) dot += p[j] * AA(j, i);
            float alpha2 = -0.5f * taui * dot;
            w[i + 1] = p[i + 1] + alpha2;
            for (int j = i + 2; j < 9; ++j) w[j] = p[j] + alpha2 * AA(j, i);
            for (int j = i + 1; j < 9; ++j) {
                float vj = (j == i + 1) ? 1.f : AA(j, i);
                for (int k2 = i + 1; k2 < 9; ++k2) {
                    float vk = (k2 == i + 1) ? 1.f : AA(k2, i);
                    AA(j, k2) -= vj * w[k2] + w[j] * vk;
                }
            }
        }
        tau[i] = taui;
    }
    for (int i = 0; i < 9; ++i) d[i] = AA(i, i);
    for (int i = 0; i < 81; ++i) Zm[i] = 0.f;
    for (int i = 0; i < 9; ++i) ZZ(i, i) = 1.f;
    const float eps = 5.9604645e-08f;
    const float eps2 = 3.5527137e-15f;
    const float safmin = 1.17549435e-38f;
    const int n = 9;
    int nmaxit = n * 30, jtot = 0;
    int l1 = 0;
    while (l1 <= n - 1) {
        if (l1 > 0) e[l1 - 1] = 0.f;
        int m = n - 1;
        for (int mm = l1; mm <= n - 2; ++mm) {
            float tst = fabsf(e[mm]);
            if (tst == 0.f) { m = mm; break; }
            if (tst <= (sqrtf(fabsf(d[mm])) * sqrtf(fabsf(d[mm + 1]))) * eps) { e[mm] = 0.f; m = mm; break; }
        }
        int l = l1, lsv = l, lend = m, lendsv = lend;
        l1 = m + 1;
        if (lend == l) continue;
        if (fabsf(d[lend]) < fabsf(d[l])) { lend = lsv; l = lendsv; }
        if (lend > l) {
            for (;;) {
                int m2 = lend;
                if (l != lend) {
                    for (int mm = l; mm <= lend - 1; ++mm) {
                        float tst = e[mm] * e[mm];
                        if (tst <= (eps2 * fabsf(d[mm])) * fabsf(d[mm + 1]) + safmin) { m2 = mm; break; }
                    }
                }
                if (m2 < lend) e[m2] = 0.f;
                float p = d[l];
                if (m2 == l) { d[l] = p; ++l; if (l <= lend) continue; else break; }
                if (m2 == l + 1) {
                    float rt1, rt2, c, s;
                    slaev2_f(d[l], e[l], d[l + 1], rt1, rt2, c, s);
                    for (int r2 = 0; r2 < 9; ++r2) {
                        float tmp = ZZ(r2, l + 1);
                        ZZ(r2, l + 1) = c * tmp - s * ZZ(r2, l);
                        ZZ(r2, l) = s * tmp + c * ZZ(r2, l);
                    }
                    d[l] = rt1; d[l + 1] = rt2; e[l] = 0.f; l += 2;
                    if (l <= lend) continue; else break;
                }
                if (jtot == nmaxit) break;
                ++jtot;
                float g = (d[l + 1] - p) / (2.f * e[l]);
                float r = slapy2_f(g, 1.f);
                g = d[m2] - p + e[l] / (g + (g >= 0.f ? fabsf(r) : -fabsf(r)));
                float s = 1.f, c = 1.f;
                p = 0.f;
                float csv[9], snv[9];
                for (int i = m2 - 1; i >= l; --i) {
                    float f = s * e[i], bq = c * e[i];
                    slartg_f(g, f, c, s, r);
                    if (i != m2 - 1) e[i + 1] = r;
                    g = d[i + 1] - p;
                    r = (d[i] - g) * s + 2.f * c * bq;
                    p = s * r;
                    d[i + 1] = g + p;
                    g = c * r - bq;
                    csv[i] = c; snv[i] = -s;
                }
                for (int jj = m2 - 1; jj >= l; --jj) {
                    float cj = csv[jj], sj = snv[jj];
                    for (int r2 = 0; r2 < 9; ++r2) {
                        float tmp = ZZ(r2, jj + 1);
                        ZZ(r2, jj + 1) = cj * tmp - sj * ZZ(r2, jj);
                        ZZ(r2, jj) = sj * tmp + cj * ZZ(r2, jj);
                    }
                }
                d[l] -= p; e[l] = g;
            }
        } else {
            for (;;) {
                int m2 = lend;
                if (l != lend) {
                    for (int mm = l; mm >= lend + 1; --mm) {
                        float tst = e[mm - 1] * e[mm - 1];
                        if (tst <= (eps2 * fabsf(d[mm])) * fabsf(d[mm - 1]) + safmin) { m2 = mm; break; }
                    }
                }
                if (m2 > lend) e[m2 - 1] = 0.f;
                float p = d[l];
                if (m2 == l) { d[l] = p; --l; if (l >= lend) continue; else break; }
                if (m2 == l - 1) {
                    float rt1, rt2, c, s;
                    slaev2_f(d[l - 1], e[l - 1], d[l], rt1, rt2, c, s);
                    for (int r2 = 0; r2 < 9; ++r2) {
                        float tmp = ZZ(r2, l);
                        ZZ(r2, l) = c * tmp - s * ZZ(r2, l - 1);
                        ZZ(r2, l - 1) = s * tmp + c * ZZ(r2, l - 1);
                    }
                    d[l - 1] = rt1; d[l] = rt2; e[l - 1] = 0.f; l -= 2;
                    if (l >= lend) continue; else break;
                }
                if (jtot == nmaxit) break;
                ++jtot;
                float g = (d[l - 1] - p) / (2.f * e[l - 1]);
                float r = slapy2_f(g, 1.f);
                g = d[m2] - p + e[l - 1] / (g + (g >= 0.f ? fabsf(r) : -fabsf(r)));
                float s = 1.f, c = 1.f;
                p = 0.f;
                float csv[9], snv[9];
                for (int i = m2; i <= l - 1; ++i) {
                    float f = s * e[i], bq = c * e[i];
                    slartg_f(g, f, c, s, r);
                    if (i != m2) e[i - 1] = r;
                    g = d[i] - p;
                    r = (d[i + 1] - g) * s + 2.f * c * bq;
                    p = s * r;
                    d[i] = g + p;
                    g = c * r - bq;
                    csv[i] = c; snv[i] = s;
                }
                for (int jj = m2; jj <= l - 1; ++jj) {
                    float cj = csv[jj], sj = snv[jj];
                    for (int r2 = 0; r2 < 9; ++r2) {
                        float tmp = ZZ(r2, jj + 1);
                        ZZ(r2, jj + 1) = cj * tmp - sj * ZZ(r2, jj);
                        ZZ(r2, jj) = sj * tmp + cj * ZZ(r2, jj);
                    }
                }
                d[l] -= p; e[l - 1] = g;
            }
        }
    }
    for (int ii = 1; ii < 9; ++ii) {
        int i = ii - 1, kk = i;
        float p = d[i];
        for (int j = ii; j < 9; ++j)
            if (d[j] < p) { kk = j; p = d[j]; }
        if (kk != i) {
            d[kk] = d[i]; d[i] = p;
            for (int r2 = 0; r2 < 9; ++r2) { float tmp = ZZ(r2, i); ZZ(r2, i) = ZZ(r2, kk); ZZ(r2, kk) = tmp; }
        }
    }
    float v0[9];
    for (int r2 = 0; r2 < 9; ++r2) v0[r2] = ZZ(r2, 0);
    for (int i = 7; i >= 0; --i) {
        float ti = tau[i];
        if (ti == 0.f) continue;
        float dot = v0[i + 1];
        for (int j = i + 2; j < 9; ++j) dot += AA(j, i) * v0[j];
        dot *= ti;
        v0[i + 1] -= dot;
        for (int j = i + 2; j < 9; ++j) v0[j] -= AA(j, i) * dot;
    }
    float nrm = 0.f;
    for (int r2 = 0; r2 < 9; ++r2) nrm += v0[r2] * v0[r2];
    nrm = sqrtf(nrm);
    for (int r2 = 0; r2 < 9; ++r2) out_e[bb * 9 + r2] = v0[r2] / nrm;
#undef AA
#undef ZZ
}

// ---------------------------------------------------------------------------
// launch
// ---------------------------------------------------------------------------
extern "C" void kernel_launch(void* const* d_in, const int* in_sizes, int n_in,
                              void* d_out, int out_size, void* d_ws, size_t ws_size,
                              hipStream_t stream) {
    const float* data = (const float*)d_in[0];
    const float* x_in = (const float*)d_in[1];
    const float* w1a = (const float*)d_in[2];
    const float* b1a = (const float*)d_in[3];
    const float* w1b = (const float*)d_in[4];
    const float* b1b = (const float*)d_in[5];
    const float* w2 = (const float*)d_in[6];
    const float* b2 = (const float*)d_in[7];
    const float* res_wa = (const float*)d_in[8];
    const float* res_ba = (const float*)d_in[9];
    const float* res_wb = (const float*)d_in[10];
    const float* res_bb = (const float*)d_in[11];
    const float* wl = (const float*)d_in[12];
    const float* bl = (const float*)d_in[13];
    float* out = (float*)d_out;

    // workspace layout
    double* gacc = (double*)d_ws;                       // 65 doubles (needs memset)
    float* xwx = (float*)((char*)d_ws + 1024);          // 16*45 floats
    float* fbase = (float*)((char*)d_ws + 8192);
    float* big0 = fbase;
    float* big1 = big0 + BB * CH * NN;
    float* big2 = big1 + BB * CH * NN;
    float* tbuf = big2 + BB * CH * NN;
    float* f5 = tbuf + BB * 4 * NN;
    float* invn = f5 + BB * 5 * NN;
    float* Sv = invn + BB * NN;
    int* idxb = (int*)(Sv + BB * CH);
    float* chAB = (float*)(idxb + BB * NN * 8);
    float* stA = chAB + 256;
    float* abA = stA + BB * CH * 2;
    float* stB = abA + BB * CH * 2;
    float* abB = stB + BB * CH * 2;
    float* g2ab = abB + BB * CH * 2;
    // kNN partials live in big2 (free until the res-blocks)
    float* knn_pd = big2;
    int* knn_pj = (int*)(big2 + BB * NN * JCH * 8);

    hipMemsetAsync(d_ws, 0, 1024, stream);

    k_build_t<<<500, 256, 0, stream>>>(data, tbuf);
    k_conv1<<<16000, 256, 0, stream>>>(tbuf, w1a, b1a, big0);
    k_chanstats<<<128, 256, 0, stream>>>(big0, chAB);
    k_gemm<<<dim3(2, 512), 256, 0, stream>>>(big0, w1b, b1b, big1, chAB, 1);  // h2 in big1
    k_invn<<<128, 256, 0, stream>>>(big1, invn);
    k_S<<<2048, 256, 0, stream>>>(big1, invn, Sv);
    k_Df<<<128, 256, 0, stream>>>(big1, invn, Sv, tbuf, out, f5);
    k_knn_part<<<dim3(JCH, 8, BB), 256, 0, stream>>>(f5, knn_pd, knn_pj);
    k_knn_merge<<<125, 256, 0, stream>>>(knn_pd, knn_pj, idxb);
    k_gstats<<<125, 256, 0, stream>>>(f5, idxb, gacc);
    k_gfinal<<<1, 128, 0, stream>>>(gacc, w2, b2, g2ab);
    k_graphconv<<<2000, 256, 0, stream>>>(f5, idxb, w2, b2, g2ab, big0);  // x0 in big0

    float* xb = big0;
    float* hb = big1;
    for (int i = 0; i < 4; ++i) {
        k_gemm<<<dim3(2, 512), 256, 0, stream>>>(xb, res_wa + i * CH * CH, res_ba + i * CH, hb, nullptr, 0);
        k_rowstats<<<2048, 256, 0, stream>>>(hb, stA);
        k_finalize<<<1, 128, 0, stream>>>(stA, abA);
        k_gemm<<<dim3(2, 512), 256, 0, stream>>>(hb, res_wb + i * CH * CH, res_bb + i * CH, big2, abA, 2);
        k_rowstats<<<2048, 256, 0, stream>>>(big2, stB);
        k_finalize<<<1, 128, 0, stream>>>(stB, abB);
        k_resadd<<<16000, 256, 0, stream>>>(big2, abB, xb, hb);
        float* tmp = xb; xb = hb; hb = tmp;
    }

    k_logit<<<128, 256, 0, stream>>>(xb, wl, bl, out + BB * NN);
    k_xwx<<<16, 256, 0, stream>>>(out + BB * NN, x_in, xwx);
    k_eigh<<<16, 64, 0, stream>>>(xwx, out + 2 * BB * NN);
}

// Round 7
// 843.657 us; speedup vs baseline: 1.4641x; 1.0268x over previous
//
#include <hip/hip_runtime.h>
#include <math.h>

#define BB 16
#define NN 2000
#define CH 128
#define KNN 8
#define JCH 8
#define JSZ 250  // NN / JCH

// ---------------------------------------------------------------------------
// helpers
// ---------------------------------------------------------------------------
__device__ inline float wred(float v) {
    for (int off = 32; off > 0; off >>= 1) v += __shfl_down(v, off, 64);
    return v;
}

// ---------------------------------------------------------------------------
// stage 0: t[b,c,n] = data[b,0,n,c]
// ---------------------------------------------------------------------------
__global__ void k_build_t(const float* __restrict__ data, float* __restrict__ t) {
    int i = blockIdx.x * 256 + threadIdx.x;
    if (i >= BB * 4 * NN) return;
    int n = i % NN;
    int c = (i / NN) & 3;
    int b = i / (4 * NN);
    t[i] = data[(b * NN + n) * 4 + c];
}

// conv1: c1[b,o,n] = sum_c w1a[o,c]*t[b,c,n] + b1a[o]
__global__ void k_conv1(const float* __restrict__ t, const float* __restrict__ w1a,
                        const float* __restrict__ b1a, float* __restrict__ c1) {
    int i = blockIdx.x * 256 + threadIdx.x;  // (b*128+o)*N+n
    if (i >= BB * CH * NN) return;
    int n = i % NN;
    int rest = i / NN;
    int o = rest & 127;
    int b = rest >> 7;
    float acc = b1a[o];
    for (int c = 0; c < 4; ++c) acc += w1a[o * 4 + c] * t[(b * 4 + c) * NN + n];
    c1[i] = acc;
}

// per-channel bn stats over (b,n): 128 blocks
__global__ void k_chanstats(const float* __restrict__ src, float* __restrict__ chAB) {
    int o = blockIdx.x;
    int tid = threadIdx.x;
    float s = 0.f, ss = 0.f;
    for (int b = 0; b < BB; ++b) {
        const float* p = src + (b * CH + o) * NN;
        for (int n = tid; n < NN; n += 256) { float v = p[n]; s += v; ss += v * v; }
    }
    s = wred(s); ss = wred(ss);
    __shared__ float sh[8];
    int wid = tid >> 6, lane = tid & 63;
    if (lane == 0) { sh[wid] = s; sh[4 + wid] = ss; }
    __syncthreads();
    if (tid == 0) {
        float S0 = sh[0] + sh[1] + sh[2] + sh[3];
        float SS = sh[4] + sh[5] + sh[6] + sh[7];
        float m = S0 / (float)(BB * NN);
        float var = SS / (float)(BB * NN) - m * m;
        float a = rsqrtf(var + 1e-5f);
        chAB[o] = a;
        chAB[CH + o] = -m * a;
    }
}

// ---------------------------------------------------------------------------
// generic 128x128 GEMM over columns (b,n), with input transform.
// mode 0: raw; mode 1: relu(chAB[j]*x + chAB[128+j]); mode 2: relu(ab[(b*128+j)*2]*x + ab[..+1])
// grid: (2, B*32), block 256.  tile: 64 o x 64 n.
// FMA accumulation order is IDENTICAL to the r3 baseline — do not reorder
// (absmax margin 0.34/0.4225 depends on it).
// ---------------------------------------------------------------------------
__global__ __launch_bounds__(256) void k_gemm(const float* __restrict__ X, const float* __restrict__ W,
                                              const float* __restrict__ bias, float* __restrict__ Y,
                                              const float* __restrict__ ab, int mode) {
    int ot = blockIdx.x, by = blockIdx.y;
    int b = by >> 5, nt = by & 31;
    int n0 = nt * 64, o0 = ot * 64;
    int tid = threadIdx.x;
    int tx = tid & 15, ty = tid >> 4;
    __shared__ float Xs[32][64];
    __shared__ float Ws[32][68];
    float acc[4][4] = {};
    for (int jc = 0; jc < 4; ++jc) {
        for (int q = 0; q < 8; ++q) {
            int e = q * 256 + tid;
            int jj = e >> 6, nn = e & 63;
            int j = jc * 32 + jj, n = n0 + nn;
            float v = 0.f;
            if (n < NN) {
                v = X[(b * CH + j) * NN + n];
                if (mode == 1) v = fmaxf(ab[j] * v + ab[CH + j], 0.f);
                else if (mode == 2) { int bc = b * CH + j; v = fmaxf(ab[bc * 2] * v + ab[bc * 2 + 1], 0.f); }
            }
            Xs[jj][nn] = v;
        }
        for (int q = 0; q < 8; ++q) {
            int e = q * 256 + tid;
            int jj = e & 31, oo = e >> 5;
            Ws[jj][oo] = W[(o0 + oo) * CH + jc * 32 + jj];
        }
        __syncthreads();
        for (int jj = 0; jj < 32; ++jj) {
            float4 wv = *(const float4*)&Ws[jj][ty * 4];
            float4 xv = *(const float4*)&Xs[jj][tx * 4];
            float wva[4] = {wv.x, wv.y, wv.z, wv.w};
            float xva[4] = {xv.x, xv.y, xv.z, xv.w};
#pragma unroll
            for (int a = 0; a < 4; ++a)
#pragma unroll
                for (int bq = 0; bq < 4; ++bq) acc[a][bq] += wva[a] * xva[bq];
        }
        __syncthreads();
    }
    for (int a = 0; a < 4; ++a) {
        int o = o0 + ty * 4 + a;
        float bi = bias[o];
        for (int q = 0; q < 4; ++q) {
            int n = n0 + tx * 4 + q;
            if (n < NN) Y[(b * CH + o) * NN + n] = acc[a][q] + bi;
        }
    }
}

// ---------------------------------------------------------------------------
// stage 1 tail: channel-norm, S, D, f5
// ---------------------------------------------------------------------------
__global__ void k_invn(const float* __restrict__ h2, float* __restrict__ invn) {
    int b = blockIdx.x >> 3, chunk = blockIdx.x & 7;
    int n = chunk * 256 + threadIdx.x;
    if (n >= NN) return;
    float acc = 0.f;
    for (int c = 0; c < CH; ++c) { float v = h2[(b * CH + c) * NN + n]; acc += v * v; }
    invn[b * NN + n] = 1.f / (sqrtf(acc) + 1e-5f);
}

__global__ void k_S(const float* __restrict__ h2, const float* __restrict__ invn, float* __restrict__ Sv) {
    int row = blockIdx.x;  // b*128+c
    int b = row >> 7;
    const float* p = h2 + row * NN;
    const float* iv = invn + b * NN;
    float s = 0.f;
    for (int n = threadIdx.x; n < NN; n += 256) s += p[n] * iv[n];
    s = wred(s);
    __shared__ float sh[4];
    int wid = threadIdx.x >> 6, lane = threadIdx.x & 63;
    if (lane == 0) sh[wid] = s;
    __syncthreads();
    if (threadIdx.x == 0) Sv[row] = sh[0] + sh[1] + sh[2] + sh[3];
}

__global__ void k_Df(const float* __restrict__ h2, const float* __restrict__ invn,
                     const float* __restrict__ Sv, const float* __restrict__ t,
                     float* __restrict__ outD, float* __restrict__ f5) {
    int b = blockIdx.x >> 3, chunk = blockIdx.x & 7;
    int n = chunk * 256 + threadIdx.x;
    if (n >= NN) return;
    float acc = 0.f;
    for (int c = 0; c < CH; ++c) acc += h2[(b * CH + c) * NN + n] * Sv[b * CH + c];
    float Ar = acc * invn[b * NN + n];
    float Dv = (Ar - 1.0f) / (float)NN;
    outD[b * NN + n] = Dv;
    for (int c = 0; c < 4; ++c) f5[(b * 5 + c) * NN + n] = t[(b * 4 + c) * NN + n];
    f5[(b * 5 + 4) * NN + n] = fmaxf(tanhf(Dv), 0.f);
}

// ---------------------------------------------------------------------------
// kNN stage A: per (b, i, j-chunk) partial top-8 over 250 candidates.
// Register-resident swap-chain top-8 (r6).  Selection semantics identical to
// the r3 stable scan.
// ---------------------------------------------------------------------------
__global__ __launch_bounds__(256) void k_knn_part(const float* __restrict__ f5,
                                                  float* __restrict__ pd, int* __restrict__ pj) {
    __shared__ float4 fs4[JSZ];
    __shared__ float fs1[JSZ];
    int jc = blockIdx.x, ic = blockIdx.y, b = blockIdx.z;
    int j0 = jc * JSZ;
    int tid = threadIdx.x;
    const float* fb = f5 + b * 5 * NN;
    for (int e = tid; e < JSZ; e += 256) {
        float4 v;
        v.x = fb[0 * NN + j0 + e];
        v.y = fb[1 * NN + j0 + e];
        v.z = fb[2 * NN + j0 + e];
        v.w = fb[3 * NN + j0 + e];
        fs4[e] = v;
        fs1[e] = fb[4 * NN + j0 + e];
    }
    __syncthreads();
    int i = ic * 256 + tid;
    if (i >= NN) return;
    float fi0 = fb[i], fi1 = fb[NN + i], fi2 = fb[2 * NN + i], fi3 = fb[3 * NN + i], fi4 = fb[4 * NN + i];
    float bd[8]; int bj[8];
#pragma unroll
    for (int q = 0; q < 8; ++q) { bd[q] = 1e30f; bj[q] = 0x7fffffff; }
    for (int jj = 0; jj < JSZ; ++jj) {
        float4 fj = fs4[jj];
        float fj4 = fs1[jj];
        int j = j0 + jj;
        float d0 = fi0 - fj.x, d1 = fi1 - fj.y, d2 = fi2 - fj.z;
        float d3 = fi3 - fj.w, d4 = fi4 - fj4;
        float d = d0 * d0 + d1 * d1 + d2 * d2 + d3 * d3 + d4 * d4;
        if (j != i && d < bd[7]) {
            float cd = d; int cj = j;
#pragma unroll
            for (int q = 0; q < 8; ++q) {
                bool lt = cd < bd[q];
                float td = lt ? bd[q] : cd;
                int tj = lt ? bj[q] : cj;
                bd[q] = lt ? cd : bd[q];
                bj[q] = lt ? cj : bj[q];
                cd = td; cj = tj;
            }
        }
    }
    long base = ((long)(b * NN + i) * JCH + jc) * 8;
#pragma unroll
    for (int q = 0; q < 8; ++q) { pd[base + q] = bd[q]; pj[base + q] = bj[q]; }
}

// kNN stage B: 8-way merge of sorted partial lists.
__global__ __launch_bounds__(256) void k_knn_merge(const float* __restrict__ pd, const int* __restrict__ pj,
                                                   int* __restrict__ idxb) {
    int s = blockIdx.x * 256 + threadIdx.x;  // b*NN + i
    if (s >= BB * NN) return;
    const float* dl = pd + (long)s * JCH * 8;
    const int* jl = pj + (long)s * JCH * 8;
    int ptr[JCH];
#pragma unroll
    for (int c = 0; c < JCH; ++c) ptr[c] = 0;
    for (int q = 0; q < 8; ++q) {
        float best = 1e38f; int bestj = 0x7fffffff; int bc = 0;
#pragma unroll
        for (int c = 0; c < JCH; ++c) {
            if (ptr[c] < 8) {
                float d = dl[c * 8 + ptr[c]];
                int j = jl[c * 8 + ptr[c]];
                if (d < best || (d == best && j < bestj)) { best = d; bestj = j; bc = c; }
            }
        }
        idxb[s * 8 + q] = bestj;
        ++ptr[bc];
    }
}

// ---------------------------------------------------------------------------
// graph-feature statistics: 10 means + 55 second moments (f64 accumulators)
// ---------------------------------------------------------------------------
__global__ __launch_bounds__(256) void k_gstats(const float* __restrict__ f5, const int* __restrict__ idxb,
                                                double* __restrict__ gacc) {
    int s = blockIdx.x * 256 + threadIdx.x;
    float acc[65];
#pragma unroll
    for (int q = 0; q < 65; ++q) acc[q] = 0.f;
    if (s < BB * NN) {
        int b = s / NN, n = s - b * NN;
        float fo[5];
#pragma unroll
        for (int c = 0; c < 5; ++c) fo[c] = f5[(b * 5 + c) * NN + n];
        float sd[5] = {0, 0, 0, 0, 0};
        float sdd[15];
#pragma unroll
        for (int q = 0; q < 15; ++q) sdd[q] = 0.f;
        for (int k = 0; k < 8; ++k) {
            int j = idxb[s * 8 + k];
            float df[5];
#pragma unroll
            for (int c = 0; c < 5; ++c) df[c] = fo[c] - f5[(b * 5 + c) * NN + j];
#pragma unroll
            for (int c = 0; c < 5; ++c) sd[c] += df[c];
            int t = 0;
#pragma unroll
            for (int c = 0; c < 5; ++c)
#pragma unroll
                for (int d2 = c; d2 < 5; ++d2) { sdd[t] += df[c] * df[d2]; ++t; }
        }
#pragma unroll
        for (int c = 0; c < 5; ++c) { acc[c] = 8.f * fo[c]; acc[5 + c] = sd[c]; }
        int t = 10, sc = 0;
        for (int p = 0; p < 10; ++p)
            for (int q = p; q < 10; ++q) {
                float v;
                if (q < 5) v = 8.f * fo[p] * fo[q];
                else if (p < 5) v = fo[p] * sd[q - 5];
                else { v = sdd[sc]; ++sc; }
                acc[t++] = v;
            }
    }
#pragma unroll 1
    for (int q = 0; q < 65; ++q) {
        float v = acc[q];
        for (int off = 32; off > 0; off >>= 1) v += __shfl_down(v, off, 64);
        acc[q] = v;
    }
    __shared__ float sh[4][65];
    int lane = threadIdx.x & 63, wid = threadIdx.x >> 6;
    if (lane == 0) {
        for (int q = 0; q < 65; ++q) sh[wid][q] = acc[q];
    }
    __syncthreads();
    if (threadIdx.x < 65) {
        float tot = sh[0][threadIdx.x] + sh[1][threadIdx.x] + sh[2][threadIdx.x] + sh[3][threadIdx.x];
        atomicAdd(&gacc[threadIdx.x], (double)tot);
    }
}

__global__ void k_gfinal(const double* __restrict__ gacc, const float* __restrict__ w2,
                         const float* __restrict__ b2, float* __restrict__ g2ab) {
    int o = threadIdx.x;
    if (o >= 128) return;
    double inv = 1.0 / (double)(BB * NN * 8);
    double Wr[10];
    for (int c = 0; c < 10; ++c) Wr[c] = (double)w2[o * 10 + c];
    double gm[10];
    for (int c = 0; c < 10; ++c) gm[c] = gacc[c] * inv;
    double b0 = (double)b2[o];
    double mean = b0;
    for (int c = 0; c < 10; ++c) mean += Wr[c] * gm[c];
    double e2 = b0 * b0 + 2.0 * b0 * (mean - b0);
    int t = 10;
    for (int p = 0; p < 10; ++p)
        for (int q = p; q < 10; ++q) {
            double G = gacc[t] * inv; ++t;
            double contrib = Wr[p] * Wr[q] * G;
            e2 += (p == q) ? contrib : 2.0 * contrib;
        }
    double var = e2 - mean * mean;
    double a = 1.0 / sqrt(var + 1e-5);
    g2ab[o] = (float)a;
    g2ab[128 + o] = (float)(-mean * a);
}

// graph conv + max over k + bn + relu (bn commutes with max since scale>0)
__global__ __launch_bounds__(256) void k_graphconv(const float* __restrict__ f5, const int* __restrict__ idxb,
                                                   const float* __restrict__ w2, const float* __restrict__ b2,
                                                   const float* __restrict__ g2ab, float* __restrict__ x0) {
    __shared__ float ws[1280], bs[128];
    __shared__ float fo_s[16][5], fnb_s[16][8][5];
    __shared__ int idxs[16][8];
    int b = blockIdx.x / 125, tile = blockIdx.x % 125;
    int nbase = tile * 16;
    int tid = threadIdx.x;
    for (int e = tid; e < 1280; e += 256) ws[e] = w2[e];
    if (tid < 128) bs[tid] = b2[tid];
    if (tid < 128) { int nn = tid >> 3, k = tid & 7; idxs[nn][k] = idxb[(b * NN + nbase + nn) * 8 + k]; }
    if (tid >= 128 && tid < 208) { int e = tid - 128; int nn = e / 5, c = e % 5; fo_s[nn][c] = f5[(b * 5 + c) * NN + nbase + nn]; }
    __syncthreads();
    for (int e = tid; e < 640; e += 256) {
        int nn = e / 40, r = e % 40, k = r / 5, c = r % 5;
        fnb_s[nn][k][c] = f5[(b * 5 + c) * NN + idxs[nn][k]];
    }
    __syncthreads();
    int nn = tid & 15, og = tid >> 4;
    float fo[5];
#pragma unroll
    for (int c = 0; c < 5; ++c) fo[c] = fo_s[nn][c];
    for (int oo = 0; oo < 8; ++oo) {
        int o = og * 8 + oo;
        float base = bs[o];
        float wn[5];
#pragma unroll
        for (int c = 0; c < 5; ++c) {
            float w1 = ws[o * 10 + c], w5 = ws[o * 10 + 5 + c];
            base += (w1 + w5) * fo[c];
            wn[c] = w5;
        }
        float mx = -1e30f;
        for (int k = 0; k < 8; ++k) {
            float v = base;
#pragma unroll
            for (int c = 0; c < 5; ++c) v -= wn[c] * fnb_s[nn][k][c];
            mx = fmaxf(mx, v);
        }
        float y = fmaxf(g2ab[o] * mx + g2ab[128 + o], 0.f);
        x0[(b * CH + o) * NN + nbase + nn] = y;
    }
}

// ---------------------------------------------------------------------------
// res-block support
// ---------------------------------------------------------------------------
__global__ void k_rowstats(const float* __restrict__ src, float* __restrict__ stats) {
    int row = blockIdx.x;  // b*128+c
    const float* p = src + row * NN;
    float s = 0.f, ss = 0.f;
    for (int n = threadIdx.x; n < NN; n += 256) { float v = p[n]; s += v; ss += v * v; }
    s = wred(s); ss = wred(ss);
    __shared__ float sh[8];
    int wid = threadIdx.x >> 6, lane = threadIdx.x & 63;
    if (lane == 0) { sh[wid] = s; sh[4 + wid] = ss; }
    __syncthreads();
    if (threadIdx.x == 0) {
        float S0 = sh[0] + sh[1] + sh[2] + sh[3];
        float SS = sh[4] + sh[5] + sh[6] + sh[7];
        float m = S0 / (float)NN;
        float var = SS / (float)NN - m * m;
        stats[row * 2] = m;
        stats[row * 2 + 1] = var;
    }
}

// instn + bn folded into per-(b,c) affine
__global__ void k_finalize(const float* __restrict__ stats, float* __restrict__ ab) {
    int c = threadIdx.x;
    if (c >= 128) return;
    float acc = 0.f;
    for (int b = 0; b < BB; ++b) { float var = stats[(b * CH + c) * 2 + 1]; acc += var / (var + 1e-5f); }
    float vc = acc / (float)BB;
    float sc = rsqrtf(vc + 1e-5f);
    for (int b = 0; b < BB; ++b) {
        float m = stats[(b * CH + c) * 2];
        float var = stats[(b * CH + c) * 2 + 1];
        float a = rsqrtf(var + 1e-5f) * sc;
        ab[(b * CH + c) * 2] = a;
        ab[(b * CH + c) * 2 + 1] = -m * a;
    }
}

__global__ void k_resadd(const float* __restrict__ Bm, const float* __restrict__ ab,
                         const float* __restrict__ x, float* __restrict__ y) {
    int i = blockIdx.x * 256 + threadIdx.x;
    if (i >= BB * CH * NN) return;
    int bc = i / NN;
    float v = ab[bc * 2] * Bm[i] + ab[bc * 2 + 1] + x[i];
    y[i] = fmaxf(v, 0.f);
}

// ---------------------------------------------------------------------------
// logit + weighted XwX
// ---------------------------------------------------------------------------
__global__ void k_logit(const float* __restrict__ x4, const float* __restrict__ wl,
                        const float* __restrict__ bl, float* __restrict__ outLogit) {
    int b = blockIdx.x >> 3, chunk = blockIdx.x & 7;
    int n = chunk * 256 + threadIdx.x;
    if (n >= NN) return;
    float acc = 0.f;
    for (int c = 0; c < CH; ++c) acc += wl[c] * x4[(b * CH + c) * NN + n];
    outLogit[b * NN + n] = acc + bl[0];
}

__global__ __launch_bounds__(256) void k_xwx(const float* __restrict__ logit, const float* __restrict__ x_in,
                                             float* __restrict__ XwX) {
    int b = blockIdx.x;
    int tid = threadIdx.x;
    float a[45];
#pragma unroll
    for (int q = 0; q < 45; ++q) a[q] = 0.f;
    for (int n = tid; n < NN; n += 256) {
        float lg = logit[b * NN + n];
        float w = fmaxf(tanhf(lg), 0.f);
        const float* xp = x_in + (b * NN + n) * 4;
        float px = xp[0], py = xp[1], z = xp[2], wq = xp[3];
        float X9[9] = {z * px, z * py, z, wq * px, wq * py, wq, px, py, 1.f};
        int t = 0;
#pragma unroll
        for (int p = 0; p < 9; ++p) {
            float wp = w * X9[p];
#pragma unroll
            for (int q = p; q < 9; ++q) { a[t] += wp * X9[q]; ++t; }
        }
    }
#pragma unroll 1
    for (int q = 0; q < 45; ++q) {
        float v = a[q];
        for (int off = 32; off > 0; off >>= 1) v += __shfl_down(v, off, 64);
        a[q] = v;
    }
    __shared__ float sh[4][45];
    int lane = tid & 63, wid = tid >> 6;
    if (lane == 0) {
        for (int q = 0; q < 45; ++q) sh[wid][q] = a[q];
    }
    __syncthreads();
    if (tid < 45) XwX[b * 45 + tid] = sh[0][tid] + sh[1][tid] + sh[2][tid] + sh[3][tid];
}

// ---------------------------------------------------------------------------
// 9x9 symmetric eigensolver — faithful LAPACK ssyevd (f32) emulation:
// ssytd2 (lower) + ssteqr + sormtr, f32 LAPACK constants, 3.10+ slartg.
// One matrix per block (r5); register top-8 kNN analog r6.
// r7 restructure: Z is never maintained.  Every Z update in ssteqr (QL sweep
// rotations, QR sweep rotations, slaev2 2x2) has the identical column form
// Z <- Z*R(j,j+1;c,s), and the d/e trajectory never reads Z.  So we LOG
// (c,s,j) triples during the sweep (fire-and-forget LDS writes) and, after
// simulating the selection sort on d[] with an index permutation, compute
// only the needed final column:  col_k(R_1...R_m) = R_1(R_2(...(R_m e_k))),
// replayed on 9 registers with a switch on wave-uniform j (static reg
// indices, 4 FMA/rotation).  d/e trajectory, sort, and sign are bit-exact;
// the replayed vector differs from maintained-Z only in summation order
// (~1e-6, consumed by no discrete decision).  r6 cost was ~300 rotations x
// 9 rows x 4 dependent LDS ops at ~120cyc — that term is gone.
// ---------------------------------------------------------------------------
__device__ inline float slapy2_f(float x, float y) {
    float xa = fabsf(x), ya = fabsf(y);
    float w = fmaxf(xa, ya), z = fminf(xa, ya);
    if (z == 0.f) return w;
    float q = z / w;
    return w * sqrtf(1.f + q * q);
}

__device__ inline void slartg_f(float f, float g, float& c, float& s, float& r) {
    if (g == 0.f) { c = 1.f; s = 0.f; r = f; }
    else if (f == 0.f) { c = 0.f; s = (g > 0.f ? 1.f : -1.f); r = fabsf(g); }
    else {
        float d = sqrtf(f * f + g * g);
        c = fabsf(f) / d;
        r = (f >= 0.f) ? d : -d;
        s = g / r;
    }
}

__device__ void slaev2_f(float a, float b, float c, float& rt1, float& rt2, float& cs1, float& sn1) {
    float sm = a + c, df = a - c;
    float adf = fabsf(df), tb = b + b, ab = fabsf(tb);
    float acmx, acmn;
    if (fabsf(a) > fabsf(c)) { acmx = a; acmn = c; } else { acmx = c; acmn = a; }
    float rt;
    if (adf > ab) { float q = ab / adf; rt = adf * sqrtf(1.f + q * q); }
    else if (adf < ab) { float q = adf / ab; rt = ab * sqrtf(1.f + q * q); }
    else rt = ab * sqrtf(2.f);
    int sgn1;
    if (sm < 0.f) { rt1 = 0.5f * (sm - rt); sgn1 = -1; rt2 = (acmx / rt1) * acmn - (b / rt1) * b; }
    else if (sm > 0.f) { rt1 = 0.5f * (sm + rt); sgn1 = 1; rt2 = (acmx / rt1) * acmn - (b / rt1) * b; }
    else { rt1 = 0.5f * rt; rt2 = -0.5f * rt; sgn1 = 1; }
    float cs; int sgn2;
    if (df >= 0.f) { cs = df + rt; sgn2 = 1; } else { cs = df - rt; sgn2 = -1; }
    float acs = fabsf(cs);
    if (acs > ab) {
        float ct = -tb / cs;
        sn1 = 1.f / sqrtf(1.f + ct * ct);
        cs1 = ct * sn1;
    } else {
        if (ab == 0.f) { cs1 = 1.f; sn1 = 0.f; }
        else { float tn = -cs / tb; cs1 = 1.f / sqrtf(1.f + tn * tn); sn1 = tn * cs1; }
    }
    if (sgn1 == sgn2) { float tn = cs1; cs1 = -sn1; sn1 = tn; }
}

#define ROTLOG_MAX 2560

__global__ __launch_bounds__(64) void k_eigh(const float* __restrict__ XwX, float* __restrict__ out_e) {
    __shared__ float Am[81];
    __shared__ float dsh[9], esh[9], tsh[9];
    __shared__ float rc[ROTLOG_MAX], rs[ROTLOG_MAX];
    __shared__ int rj[ROTLOG_MAX];
    int bb = blockIdx.x;
    if (threadIdx.x != 0) return;
    float* d = dsh;
    float* e = esh;
    float* tau = tsh;
    int cnt = 0;
#define AA(i, j) Am[(i) * 9 + (j)]
    {
        const float* src = XwX + bb * 45;
        int t = 0;
        for (int p = 0; p < 9; ++p)
            for (int q = p; q < 9; ++q) { float v = src[t++]; AA(p, q) = v; AA(q, p) = v; }
    }
    // --- ssytd2 (lower) ---
    for (int i = 0; i < 8; ++i) {
        float alpha = AA(i + 1, i);
        float xn2 = 0.f;
        for (int j = i + 2; j < 9; ++j) xn2 += AA(j, i) * AA(j, i);
        float taui;
        if (xn2 == 0.f) { taui = 0.f; e[i] = alpha; }
        else {
            float xnorm = sqrtf(xn2);
            float beta = slapy2_f(alpha, xnorm);
            beta = (alpha >= 0.f) ? -beta : beta;
            taui = (beta - alpha) / beta;
            float scl = 1.f / (alpha - beta);
            for (int j = i + 2; j < 9; ++j) AA(j, i) *= scl;
            e[i] = beta;
            float p[9], w[9];
            for (int j = i + 1; j < 9; ++j) {
                float acc = AA(j, i + 1);
                for (int k2 = i + 2; k2 < 9; ++k2) acc += AA(j, k2) * AA(k2, i);
                p[j] = taui * acc;
            }
            float dot = p[i + 1];
            for (int j = i + 2; j < 9; ++j) dot += p[j] * AA(j, i);
            float alpha2 = -0.5f * taui * dot;
            w[i + 1] = p[i + 1] + alpha2;
            for (int j = i + 2; j < 9; ++j) w[j] = p[j] + alpha2 * AA(j, i);
            for (int j = i + 1; j < 9; ++j) {
                float vj = (j == i + 1) ? 1.f : AA(j, i);
                for (int k2 = i + 1; k2 < 9; ++k2) {
                    float vk = (k2 == i + 1) ? 1.f : AA(k2, i);
                    AA(j, k2) -= vj * w[k2] + w[j] * vk;
                }
            }
        }
        tau[i] = taui;
    }
    for (int i = 0; i < 9; ++i) d[i] = AA(i, i);
    // --- ssteqr (rotation-logging; Z never materialized) ---
    const float eps = 5.9604645e-08f;
    const float eps2 = 3.5527137e-15f;
    const float safmin = 1.17549435e-38f;
    const int n = 9;
    int nmaxit = n * 30, jtot = 0;
    int l1 = 0;
    while (l1 <= n - 1) {
        if (l1 > 0) e[l1 - 1] = 0.f;
        int m = n - 1;
        for (int mm = l1; mm <= n - 2; ++mm) {
            float tst = fabsf(e[mm]);
            if (tst == 0.f) { m = mm; break; }
            if (tst <= (sqrtf(fabsf(d[mm])) * sqrtf(fabsf(d[mm + 1]))) * eps) { e[mm] = 0.f; m = mm; break; }
        }
        int l = l1, lsv = l, lend = m, lendsv = lend;
        l1 = m + 1;
        if (lend == l) continue;
        if (fabsf(d[lend]) < fabsf(d[l])) { lend = lsv; l = lendsv; }
        if (lend > l) {
            // QL
            for (;;) {
                int m2 = lend;
                if (l != lend) {
                    for (int mm = l; mm <= lend - 1; ++mm) {
                        float tst = e[mm] * e[mm];
                        if (tst <= (eps2 * fabsf(d[mm])) * fabsf(d[mm + 1]) + safmin) { m2 = mm; break; }
                    }
                }
                if (m2 < lend) e[m2] = 0.f;
                float p = d[l];
                if (m2 == l) { d[l] = p; ++l; if (l <= lend) continue; else break; }
                if (m2 == l + 1) {
                    float rt1, rt2, c, s;
                    slaev2_f(d[l], e[l], d[l + 1], rt1, rt2, c, s);
                    rc[cnt] = c; rs[cnt] = s; rj[cnt] = l; ++cnt;
                    d[l] = rt1; d[l + 1] = rt2; e[l] = 0.f; l += 2;
                    if (l <= lend) continue; else break;
                }
                if (jtot == nmaxit) break;
                ++jtot;
                float g = (d[l + 1] - p) / (2.f * e[l]);
                float r = slapy2_f(g, 1.f);
                g = d[m2] - p + e[l] / (g + (g >= 0.f ? fabsf(r) : -fabsf(r)));
                float s = 1.f, c = 1.f;
                p = 0.f;
                for (int i = m2 - 1; i >= l; --i) {
                    float f = s * e[i], bq = c * e[i];
                    slartg_f(g, f, c, s, r);
                    if (i != m2 - 1) e[i + 1] = r;
                    g = d[i + 1] - p;
                    r = (d[i] - g) * s + 2.f * c * bq;
                    p = s * r;
                    d[i + 1] = g + p;
                    g = c * r - bq;
                    rc[cnt] = c; rs[cnt] = -s; rj[cnt] = i; ++cnt;
                }
                d[l] -= p; e[l] = g;
            }
        } else {
            // QR
            for (;;) {
                int m2 = lend;
                if (l != lend) {
                    for (int mm = l; mm >= lend + 1; --mm) {
                        float tst = e[mm - 1] * e[mm - 1];
                        if (tst <= (eps2 * fabsf(d[mm])) * fabsf(d[mm - 1]) + safmin) { m2 = mm; break; }
                    }
                }
                if (m2 > lend) e[m2 - 1] = 0.f;
                float p = d[l];
                if (m2 == l) { d[l] = p; --l; if (l >= lend) continue; else break; }
                if (m2 == l - 1) {
                    float rt1, rt2, c, s;
                    slaev2_f(d[l - 1], e[l - 1], d[l], rt1, rt2, c, s);
                    rc[cnt] = c; rs[cnt] = s; rj[cnt] = l - 1; ++cnt;
                    d[l - 1] = rt1; d[l] = rt2; e[l - 1] = 0.f; l -= 2;
                    if (l >= lend) continue; else break;
                }
                if (jtot == nmaxit) break;
                ++jtot;
                float g = (d[l - 1] - p) / (2.f * e[l - 1]);
                float r = slapy2_f(g, 1.f);
                g = d[m2] - p + e[l - 1] / (g + (g >= 0.f ? fabsf(r) : -fabsf(r)));
                float s = 1.f, c = 1.f;
                p = 0.f;
                for (int i = m2; i <= l - 1; ++i) {
                    float f = s * e[i], bq = c * e[i];
                    slartg_f(g, f, c, s, r);
                    if (i != m2) e[i - 1] = r;
                    g = d[i] - p;
                    r = (d[i + 1] - g) * s + 2.f * c * bq;
                    p = s * r;
                    d[i] = g + p;
                    g = c * r - bq;
                    rc[cnt] = c; rs[cnt] = s; rj[cnt] = i; ++cnt;
                }
                d[l] -= p; e[l - 1] = g;
            }
        }
    }
    // selection sort ascending on d[], tracking the column permutation only
    int perm[9];
    for (int i = 0; i < 9; ++i) perm[i] = i;
    for (int ii = 1; ii < 9; ++ii) {
        int i = ii - 1, kk = i;
        float p = d[i];
        for (int j = ii; j < 9; ++j)
            if (d[j] < p) { kk = j; p = d[j]; }
        if (kk != i) {
            d[kk] = d[i]; d[i] = p;
            int tp = perm[i]; perm[i] = perm[kk]; perm[kk] = tp;
        }
    }
    int kcol = perm[0];
    // replay rotation product on 9 registers: col_k(R_1..R_m) = R_1(...(R_m e_k))
    float w0 = (kcol == 0) ? 1.f : 0.f, w1 = (kcol == 1) ? 1.f : 0.f, w2 = (kcol == 2) ? 1.f : 0.f;
    float w3 = (kcol == 3) ? 1.f : 0.f, w4 = (kcol == 4) ? 1.f : 0.f, w5 = (kcol == 5) ? 1.f : 0.f;
    float w6 = (kcol == 6) ? 1.f : 0.f, w7 = (kcol == 7) ? 1.f : 0.f, w8 = (kcol == 8) ? 1.f : 0.f;
    for (int t = cnt - 1; t >= 0; --t) {
        float c = rc[t], s = rs[t];
        int j = rj[t];
        switch (j) {
            case 0: { float a = w0, b = w1; w0 = c * a - s * b; w1 = s * a + c * b; } break;
            case 1: { float a = w1, b = w2; w1 = c * a - s * b; w2 = s * a + c * b; } break;
            case 2: { float a = w2, b = w3; w2 = c * a - s * b; w3 = s * a + c * b; } break;
            case 3: { float a = w3, b = w4; w3 = c * a - s * b; w4 = s * a + c * b; } break;
            case 4: { float a = w4, b = w5; w4 = c * a - s * b; w5 = s * a + c * b; } break;
            case 5: { float a = w5, b = w6; w5 = c * a - s * b; w6 = s * a + c * b; } break;
            case 6: { float a = w6, b = w7; w6 = c * a - s * b; w7 = s * a + c * b; } break;
            default: { float a = w7, b = w8; w7 = c * a - s * b; w8 = s * a + c * b; } break;
        }
    }
    float v0[9] = {w0, w1, w2, w3, w4, w5, w6, w7, w8};
    // back-transform by Q (sormtr 'L','L','N': apply H(8)..H(1))
    for (int i = 7; i >= 0; --i) {
        float ti = tau[i];
        if (ti == 0.f) continue;
        float dot = v0[i + 1];
        for (int j = i + 2; j < 9; ++j) dot += AA(j, i) * v0[j];
        dot *= ti;
        v0[i + 1] -= dot;
        for (int j = i + 2; j < 9; ++j) v0[j] -= AA(j, i) * dot;
    }
    float nrm = 0.f;
    for (int r2 = 0; r2 < 9; ++r2) nrm += v0[r2] * v0[r2];
    nrm = sqrtf(nrm);
    for (int r2 = 0; r2 < 9; ++r2) out_e[bb * 9 + r2] = v0[r2] / nrm;
#undef AA
}

// ---------------------------------------------------------------------------
// launch
// ---------------------------------------------------------------------------
extern "C" void kernel_launch(void* const* d_in, const int* in_sizes, int n_in,
                              void* d_out, int out_size, void* d_ws, size_t ws_size,
                              hipStream_t stream) {
    const float* data = (const float*)d_in[0];
    const float* x_in = (const float*)d_in[1];
    const float* w1a = (const float*)d_in[2];
    const float* b1a = (const float*)d_in[3];
    const float* w1b = (const float*)d_in[4];
    const float* b1b = (const float*)d_in[5];
    const float* w2 = (const float*)d_in[6];
    const float* b2 = (const float*)d_in[7];
    const float* res_wa = (const float*)d_in[8];
    const float* res_ba = (const float*)d_in[9];
    const float* res_wb = (const float*)d_in[10];
    const float* res_bb = (const float*)d_in[11];
    const float* wl = (const float*)d_in[12];
    const float* bl = (const float*)d_in[13];
    float* out = (float*)d_out;

    // workspace layout
    double* gacc = (double*)d_ws;                       // 65 doubles (needs memset)
    float* xwx = (float*)((char*)d_ws + 1024);          // 16*45 floats
    float* fbase = (float*)((char*)d_ws + 8192);
    float* big0 = fbase;
    float* big1 = big0 + BB * CH * NN;
    float* big2 = big1 + BB * CH * NN;
    float* tbuf = big2 + BB * CH * NN;
    float* f5 = tbuf + BB * 4 * NN;
    float* invn = f5 + BB * 5 * NN;
    float* Sv = invn + BB * NN;
    int* idxb = (int*)(Sv + BB * CH);
    float* chAB = (float*)(idxb + BB * NN * 8);
    float* stA = chAB + 256;
    float* abA = stA + BB * CH * 2;
    float* stB = abA + BB * CH * 2;
    float* abB = stB + BB * CH * 2;
    float* g2ab = abB + BB * CH * 2;
    // kNN partials live in big2 (free until the res-blocks)
    float* knn_pd = big2;
    int* knn_pj = (int*)(big2 + BB * NN * JCH * 8);

    hipMemsetAsync(d_ws, 0, 1024, stream);

    k_build_t<<<500, 256, 0, stream>>>(data, tbuf);
    k_conv1<<<16000, 256, 0, stream>>>(tbuf, w1a, b1a, big0);
    k_chanstats<<<128, 256, 0, stream>>>(big0, chAB);
    k_gemm<<<dim3(2, 512), 256, 0, stream>>>(big0, w1b, b1b, big1, chAB, 1);  // h2 in big1
    k_invn<<<128, 256, 0, stream>>>(big1, invn);
    k_S<<<2048, 256, 0, stream>>>(big1, invn, Sv);
    k_Df<<<128, 256, 0, stream>>>(big1, invn, Sv, tbuf, out, f5);
    k_knn_part<<<dim3(JCH, 8, BB), 256, 0, stream>>>(f5, knn_pd, knn_pj);
    k_knn_merge<<<125, 256, 0, stream>>>(knn_pd, knn_pj, idxb);
    k_gstats<<<125, 256, 0, stream>>>(f5, idxb, gacc);
    k_gfinal<<<1, 128, 0, stream>>>(gacc, w2, b2, g2ab);
    k_graphconv<<<2000, 256, 0, stream>>>(f5, idxb, w2, b2, g2ab, big0);  // x0 in big0

    float* xb = big0;
    float* hb = big1;
    for (int i = 0; i < 4; ++i) {
        k_gemm<<<dim3(2, 512), 256, 0, stream>>>(xb, res_wa + i * CH * CH, res_ba + i * CH, hb, nullptr, 0);
        k_rowstats<<<2048, 256, 0, stream>>>(hb, stA);
        k_finalize<<<1, 128, 0, stream>>>(stA, abA);
        k_gemm<<<dim3(2, 512), 256, 0, stream>>>(hb, res_wb + i * CH * CH, res_bb + i * CH, big2, abA, 2);
        k_rowstats<<<2048, 256, 0, stream>>>(big2, stB);
        k_finalize<<<1, 128, 0, stream>>>(stB, abB);
        k_resadd<<<16000, 256, 0, stream>>>(big2, abB, xb, hb);
        float* tmp = xb; xb = hb; hb = tmp;
    }

    k_logit<<<128, 256, 0, stream>>>(xb, wl, bl, out + BB * NN);
    k_xwx<<<16, 256, 0, stream>>>(out + BB * NN, x_in, xwx);
    k_eigh<<<16, 64, 0, stream>>>(xwx, out + 2 * BB * NN);
}